// Round 7
// baseline (373.375 us; speedup 1.0000x reference)
//
#include <hip/hip_runtime.h>

#define N_NODES  100000
#define N_EDGES  1600000
#define N_GRAPHS 512
#define HID      128
#define NB       196        // coarse buckets of 512 nodes (dst >> 9)
#define NCHUNK   196        // edge chunks of 8192
#define CHUNK    8192
#define ECAP     512        // LDS edge-span capacity per wave-tile (mean 272, 16-sigma headroom)

typedef unsigned int  uint;
typedef unsigned char uchar;
typedef unsigned short ushort;
typedef __attribute__((ext_vector_type(8))) short  short8;   // 8 bf16 (4 VGPRs)
typedef __attribute__((ext_vector_type(4))) float  f32x4;
typedef __attribute__((ext_vector_type(2))) float  f32x2;

__device__ inline float bflo(uint u) { return __uint_as_float(u << 16); }
__device__ inline float bfhi(uint u) { return __uint_as_float(u & 0xffff0000u); }
__device__ inline ushort f2bf(float f) {
    uint u = __float_as_uint(f);
    return (ushort)((u + 0x7fffu + ((u >> 16) & 1u)) >> 16);   // RNE
}
__device__ inline uint pk(float a, float b) {
    return (uint)f2bf(a) | ((uint)f2bf(b) << 16);
}

// weighted row accumulate; w in {0,1} masks OOB slots (norm folded into G = dinv*H)
__device__ inline void acc8_bf16(uint4 hv, float w, float* a) {
    a[0] += w * bflo(hv.x); a[1] += w * bfhi(hv.x);
    a[2] += w * bflo(hv.y); a[3] += w * bfhi(hv.y);
    a[4] += w * bflo(hv.z); a[5] += w * bfhi(hv.z);
    a[6] += w * bflo(hv.w); a[7] += w * bfhi(hv.w);
}
__device__ inline void acc8_fp8(uint2 hv, float w, float* a) {
    f32x2 p0 = __builtin_amdgcn_cvt_pk_f32_fp8((int)hv.x, false);
    f32x2 p1 = __builtin_amdgcn_cvt_pk_f32_fp8((int)hv.x, true);
    f32x2 p2 = __builtin_amdgcn_cvt_pk_f32_fp8((int)hv.y, false);
    f32x2 p3 = __builtin_amdgcn_cvt_pk_f32_fp8((int)hv.y, true);
    a[0] += w * p0.x; a[1] += w * p0.y; a[2] += w * p1.x; a[3] += w * p1.y;
    a[4] += w * p2.x; a[5] += w * p2.y; a[6] += w * p3.x; a[7] += w * p3.y;
}

// ---------------- prep: pack W | graph boundaries | cvt temb -> bf16 ----------------
// blocks: [0,224) pack, [224,615) boundary, [615,3740) temb cvt
__global__ __launch_bounds__(256)
void prep_kernel(const float* __restrict__ Wt, const float* __restrict__ W1,
                 const float* __restrict__ Ws, ushort* __restrict__ packed,
                 const int* __restrict__ batch, int* __restrict__ gstart,
                 const float* __restrict__ temb, ushort* __restrict__ tembb) {
    int b = blockIdx.x;
    int t = threadIdx.x;
    if (b < 224) {                          // pack weights into MFMA B-frag order
        int tid = b * 256 + t;
        const float* src; int p; ushort* dst;
        if (tid < 16384)      { src = Wt;         p = tid;         dst = packed; }
        else if (tid < 24576) { src = W1;         p = tid - 16384; dst = packed + 16384; }
        else if (tid < 40960) { src = Ws;         p = tid - 24576; dst = packed + 24576; }
        else                  { src = Ws + 16384; p = tid - 40960; dst = packed + 40960; }
        int j  = p & 7;
        int L  = (p >> 3) & 63;
        int cb = (p >> 9) & 7;
        int s  = p >> 12;
        int k  = s * 32 + (L >> 4) * 8 + j;
        int n  = cb * 16 + (L & 15);
        dst[p] = f2bf(src[k * 128 + n]);
    } else if (b < 615) {                   // graph boundary scan (batch sorted)
        int i = (b - 224) * 256 + t;
        if (i >= N_NODES) return;
        int bb = batch[i];
        int prev = (i == 0) ? -1 : batch[i - 1];
        for (int g = prev + 1; g <= bb; ++g) gstart[g] = i;
        if (i == N_NODES - 1) {
            for (int g = bb + 1; g <= N_GRAPHS; ++g) gstart[g] = N_NODES;
        }
    } else {                                // cvt temb (N*128 floats, 16/thread, exact)
        long i = ((long)(b - 615) * 256 + t) * 16;
#pragma unroll
        for (int k = 0; k < 4; ++k) {
            float4 f = *(const float4*)(temb + i + k * 4);
            uint2 o; o.x = pk(f.x, f.y); o.y = pk(f.z, f.w);
            *(uint2*)(tembb + i + k * 4) = o;
        }
    }
}

// ---------------- CSR build v2: 2-level bucketed counting sort ----------------

// B1: per-chunk coarse histogram (LDS only, no global atomics)
__global__ __launch_bounds__(256)
void hist_chunks(const int* __restrict__ dst, int* __restrict__ chunk_hist) {
    __shared__ int h[NB];
    int c = blockIdx.x, t = threadIdx.x;
    if (t < NB) h[t] = 0;
    __syncthreads();
    const int4* d4 = (const int4*)dst;
#pragma unroll
    for (int k = 0; k < 8; ++k) {
        int i4 = c * (CHUNK / 4) + k * 256 + t;
        if (i4 < N_EDGES / 4) {
            int4 d = d4[i4];
            atomicAdd(&h[d.x >> 9], 1);
            atomicAdd(&h[d.y >> 9], 1);
            atomicAdd(&h[d.z >> 9], 1);
            atomicAdd(&h[d.w >> 9], 1);
        }
    }
    __syncthreads();
    if (t < NB) chunk_hist[c * NB + t] = h[t];
}

// B2: single block — bucket bases + per-(chunk,bucket) bases
__global__ __launch_bounds__(256)
void scan_chunks(const int* __restrict__ chunk_hist, int* __restrict__ cbase,
                 int* __restrict__ bstart, int* __restrict__ row_ptr) {
    __shared__ int sc[256];
    int t = threadIdx.x;
    int tot = 0;
    if (t < NB)
        for (int c = 0; c < NCHUNK; ++c) tot += chunk_hist[c * NB + t];
    sc[t] = (t < NB) ? tot : 0;
    __syncthreads();
    for (int off = 1; off < 256; off <<= 1) {
        int x = (t >= off) ? sc[t - off] : 0;
        __syncthreads();
        sc[t] += x;
        __syncthreads();
    }
    int excl = sc[t] - ((t < NB) ? tot : 0);
    if (t < NB) {
        bstart[t] = excl;
        int run = excl;
        for (int c = 0; c < NCHUNK; ++c) {
            cbase[c * NB + t] = run;
            run += chunk_hist[c * NB + t];
        }
    }
    if (t == 0) { bstart[NB] = N_EDGES; row_ptr[N_NODES] = N_EDGES; }
}

// B3: per-chunk scatter into tmp — block writes contiguous runs per bucket (coalesced)
__global__ __launch_bounds__(256)
void scatter_coarse(const int* __restrict__ src, const int* __restrict__ dst,
                    const int* __restrict__ cbase, uint* __restrict__ tmp) {
    __shared__ int cur[NB];
    int c = blockIdx.x, t = threadIdx.x;
    if (t < NB) cur[t] = cbase[c * NB + t];
    __syncthreads();
    const int4* s4p = (const int4*)src;
    const int4* d4p = (const int4*)dst;
#pragma unroll
    for (int k = 0; k < 8; ++k) {
        int i4 = c * (CHUNK / 4) + k * 256 + t;
        if (i4 < N_EDGES / 4) {
            int4 s = s4p[i4];
            int4 d = d4p[i4];
            int p;
            p = atomicAdd(&cur[d.x >> 9], 1); tmp[p] = (uint)s.x | (((uint)(d.x & 511)) << 17);
            p = atomicAdd(&cur[d.y >> 9], 1); tmp[p] = (uint)s.y | (((uint)(d.y & 511)) << 17);
            p = atomicAdd(&cur[d.z >> 9], 1); tmp[p] = (uint)s.z | (((uint)(d.z & 511)) << 17);
            p = atomicAdd(&cur[d.w >> 9], 1); tmp[p] = (uint)s.w | (((uint)(d.w & 511)) << 17);
        }
    }
}

// C: one block per bucket — local hist+scan -> row_ptr/dinv, fine scatter, and fused
// xb = fp8(dinv * x)   (fp8: halves conv1's gather bytes AND this kernel's write)
__global__ __launch_bounds__(256)
void csr_fine(const uint* __restrict__ tmp, const int* __restrict__ bstart,
              int* __restrict__ row_ptr, float* __restrict__ dinv,
              int* __restrict__ edge, const float* __restrict__ x,
              uchar* __restrict__ xb8) {
    __shared__ int   cnt[512];
    __shared__ float dvloc[512];
    __shared__ int   ps[256];
    int b = blockIdx.x, t = threadIdx.x;
    int node0 = b << 9;
    int ncnt = min(512, N_NODES - node0);
    int s = bstart[b], e = bstart[b + 1];
    cnt[t] = 0; cnt[t + 256] = 0;
    __syncthreads();
    for (int i = s + t; i < e; i += 256) atomicAdd(&cnt[tmp[i] >> 17], 1);
    __syncthreads();
    int c0 = cnt[2 * t], c1 = cnt[2 * t + 1];
    int pair = c0 + c1;
    ps[t] = pair;
    __syncthreads();
    for (int off = 1; off < 256; off <<= 1) {
        int v = (t >= off) ? ps[t - off] : 0;
        __syncthreads();
        ps[t] += v;
        __syncthreads();
    }
    int ep = ps[t] - pair;                   // exclusive pair prefix
    int p0 = s + ep, p1 = s + ep + c0;
    float dv0 = rsqrtf((float)(c0 + 1));
    float dv1 = rsqrtf((float)(c1 + 1));
    int n0 = node0 + 2 * t;
    if (2 * t < ncnt)     { row_ptr[n0]     = p0; dinv[n0]     = dv0; }
    if (2 * t + 1 < ncnt) { row_ptr[n0 + 1] = p1; dinv[n0 + 1] = dv1; }
    dvloc[2 * t] = dv0; dvloc[2 * t + 1] = dv1;
    cnt[2 * t] = p0; cnt[2 * t + 1] = p1;    // convert counts -> absolute cursors
    __syncthreads();
    for (int i = s + t; i < e; i += 256) {
        uint rec = tmp[i];
        int p = atomicAdd(&cnt[rec >> 17], 1);
        edge[p] = (int)(rec & 0x1FFFFu);
    }
    // fused: xb8 rows for this bucket = fp8(dinv * x)  (4 feats -> 1 uint per idx)
    for (int idx = t; idx < ncnt * 16; idx += 256) {
        int row = idx >> 4, q = idx & 15;
        float4 f = ((const float4*)(x + (size_t)(node0 + row) * 64))[q];
        float d = dvloc[row];
        int w = __builtin_amdgcn_cvt_pk_fp8_f32(f.x * d, f.y * d, 0, false);
        w     = __builtin_amdgcn_cvt_pk_fp8_f32(f.z * d, f.w * d, w, true);
        *(uint*)(xb8 + (size_t)(node0 + row) * 64 + q * 4) = (uint)w;
    }
}

// ---------------- fused GCN conv ----------------
// input rows are G = dinv*H (fp8); agg_v = dinv_v * (sum_{s in N(v)} G_s + G_v)
// O = relu(agg @ W + b) [+ relu(tembb @ Wt + bt)]; SCALEOUT: store dinv*O
// Phase 1: ONE LANE-GROUP PER ROW (R4) + U=8 batched gathers (R5) + tile's edge span
// STAGED IN LDS (R7): contiguous CSR slice (~272 recs) loaded coalesced once; edge
// reads become ds_read (~10cy) instead of global (~200-900cy). The LDS path indexes
// the __shared__ array DIRECTLY (R6's negative-offset generic pointer was UB -> fault);
// wave-uniform if/else picks LDS vs global-fallback instantiation of the same lambda.
template <int K, bool TEMB, bool SRC8, bool OUT8, bool SCALEOUT>
__global__ __launch_bounds__(256)
void fused_conv(const void* __restrict__ Hv, const int* __restrict__ rp,
                const int* __restrict__ edge, const float* __restrict__ dinv,
                const ushort* __restrict__ Wp, const float* __restrict__ bias,
                const ushort* __restrict__ tembb, const ushort* __restrict__ Wtp,
                const float* __restrict__ bias_t, void* __restrict__ Ov, int ntiles) {
    constexpr int LPR  = K / 8;       // lanes per row (8 feats/lane)
    constexpr int G    = 64 / LPR;    // concurrent rows (lane groups)
    constexpr int RPG  = 16 / G;      // serial rows per group
    constexpr int U    = SRC8 ? 8 : 4;// edge-walk unroll depth
    constexpr int LROW = 136;         // LDS row stride in shorts (bf16 staging)
    __shared__ __align__(16) ushort sA[4][16 * LROW];
    __shared__ uint sE[4][ECAP];      // per-wave edge-span stage
    const int wave = threadIdx.x >> 6;
    const int lane = threadIdx.x & 63;
    const int tile = blockIdx.x * 4 + wave;
    if (tile >= ntiles) return;       // per-wave LDS, no barriers: safe
    const int row0 = tile * 16;
    const int g  = lane / LPR;
    const int fq = lane % LPR;
    ushort* myA = sA[wave];
    const ushort* Hb = (const ushort*)Hv;
    const uchar*  H8 = (const uchar*)Hv;

    // lane-parallel preload of row_ptr[17] / dinv[16]; broadcast via shfl
    int   rpv = rp[row0 + ((lane < 17) ? lane : 16)];
    float dvv = dinv[row0 + ((lane < 16) ? lane : 15)];

    // ---- stage the tile's contiguous edge span into LDS (coalesced) ----
    const int s0   = __shfl(rpv, 0);
    const int e15  = __shfl(rpv, 16);
    const int ecnt = e15 - s0;
    uint* sEw = sE[wave];
    for (int i = lane; i < ecnt && i < ECAP; i += 64)
        sEw[i] = ((const uint*)edge)[s0 + i];

    // ---- phase 1: each group gathers its own RPG rows (no cross-group reduce) ----
    auto phase1 = [&](auto eload) {
        for (int rr = 0; rr < RPG; ++rr) {
            int r = g * RPG + rr;
            int v = row0 + r;
            int s = __shfl(rpv, r), e = __shfl(rpv, r + 1);
            float a[8];
            // self-loop init: a = G_v
            if constexpr (!SRC8) {
                uint4 xv = *(const uint4*)(Hb + (size_t)v * K + fq * 8);
                a[0] = bflo(xv.x); a[1] = bfhi(xv.x);
                a[2] = bflo(xv.y); a[3] = bfhi(xv.y);
                a[4] = bflo(xv.z); a[5] = bfhi(xv.z);
                a[6] = bflo(xv.w); a[7] = bfhi(xv.w);
            } else {
                uint2 xv = *(const uint2*)(H8 + (size_t)v * K + fq * 8);
                f32x2 p0 = __builtin_amdgcn_cvt_pk_f32_fp8((int)xv.x, false);
                f32x2 p1 = __builtin_amdgcn_cvt_pk_f32_fp8((int)xv.x, true);
                f32x2 p2 = __builtin_amdgcn_cvt_pk_f32_fp8((int)xv.y, false);
                f32x2 p3 = __builtin_amdgcn_cvt_pk_f32_fp8((int)xv.y, true);
                a[0] = p0.x; a[1] = p0.y; a[2] = p1.x; a[3] = p1.y;
                a[4] = p2.x; a[5] = p2.y; a[6] = p3.x; a[7] = p3.y;
            }
            int iters = (e - s + U - 1) / U;  // group-uniform; U-deep unrolled walk
            int j = s;
            for (int i = 0; i < iters; ++i, j += U) {
                int sv[U]; float wv[U];
#pragma unroll
                for (int u = 0; u < U; ++u) {
                    int jv = j + u;
                    int jj = (jv < e) ? jv : e - 1;   // iters>0 => e>s => e-1 valid
                    sv[u] = eload(jj);
                    wv[u] = (jv < e) ? 1.0f : 0.0f;
                }
                if constexpr (!SRC8) {
                    uint4 hv[U];
#pragma unroll
                    for (int u = 0; u < U; ++u)
                        hv[u] = *(const uint4*)(Hb + (size_t)sv[u] * K + fq * 8);
#pragma unroll
                    for (int u = 0; u < U; ++u) acc8_bf16(hv[u], wv[u], a);
                } else {
                    uint2 hv[U];
#pragma unroll
                    for (int u = 0; u < U; ++u)
                        hv[u] = *(const uint2*)(H8 + (size_t)sv[u] * K + fq * 8);
#pragma unroll
                    for (int u = 0; u < U; ++u) acc8_fp8(hv[u], wv[u], a);
                }
            }
            float dv = __shfl(dvv, r);        // row-uniform scale
            uint4 o;
            o.x = pk(a[0] * dv, a[1] * dv); o.y = pk(a[2] * dv, a[3] * dv);
            o.z = pk(a[4] * dv, a[5] * dv); o.w = pk(a[6] * dv, a[7] * dv);
            *(uint4*)(myA + r * LROW + fq * 8) = o;
        }
    };
    if (ecnt <= ECAP) {
        phase1([&](int jj) { return (int)sEw[jj - s0]; });       // LDS path (normal)
    } else {
        phase1([&](int jj) { return (int)((const uint*)edge)[jj]; });  // fallback
    }

    // ---- phase 2: MFMA (A from LDS, B packed from global/L2) ----
    const int m = lane & 15, q = lane >> 4;
    f32x4 acc[8];
#pragma unroll
    for (int cb = 0; cb < 8; ++cb) acc[cb] = {0.f, 0.f, 0.f, 0.f};
    constexpr int S = K / 32;
#pragma unroll
    for (int s = 0; s < S; ++s) {
        short8 av = *(const short8*)(myA + m * LROW + s * 32 + q * 8);
#pragma unroll
        for (int cb = 0; cb < 8; ++cb) {
            short8 b = *(const short8*)(Wp + (size_t)((s * 8 + cb) * 64 + lane) * 8);
            acc[cb] = __builtin_amdgcn_mfma_f32_16x16x32_bf16(av, b, acc[cb], 0, 0, 0);
        }
    }

    // ---- phase 2b (TEMB): second MFMA chain, A = prepacked bf16 temb rows ----
    f32x4 acc2[TEMB ? 8 : 1];
    if constexpr (TEMB) {
#pragma unroll
        for (int cb = 0; cb < 8; ++cb) acc2[cb] = {0.f, 0.f, 0.f, 0.f};
        const ushort* Arow = tembb + (size_t)(row0 + m) * 128 + q * 8;
#pragma unroll
        for (int s2 = 0; s2 < 4; ++s2) {
            short8 av = *(const short8*)(Arow + s2 * 32);
#pragma unroll
            for (int cb = 0; cb < 8; ++cb) {
                short8 b = *(const short8*)(Wtp + (size_t)((s2 * 8 + cb) * 64 + lane) * 8);
                acc2[cb] = __builtin_amdgcn_mfma_f32_16x16x32_bf16(av, b, acc2[cb], 0, 0, 0);
            }
        }
    }

    // ---- phase 3: epilogue into LDS, coalesced store ----
    // C/D layout: col = lane&15, row = (lane>>4)*4 + r
    float dsc[4];
    if constexpr (SCALEOUT) {
#pragma unroll
        for (int r = 0; r < 4; ++r) dsc[r] = __shfl(dvv, q * 4 + r);
    }
    if constexpr (!OUT8) {
        ushort* Ob = (ushort*)Ov;
#pragma unroll
        for (int cb = 0; cb < 8; ++cb) {
            int colc = cb * 16 + m;
            float bv = bias[colc];
            float bt2 = TEMB ? bias_t[colc] : 0.f;
#pragma unroll
            for (int r = 0; r < 4; ++r) {
                int row = q * 4 + r;
                float v = fmaxf(acc[cb][r] + bv, 0.0f);
                if (TEMB) v += fmaxf(acc2[cb][r] + bt2, 0.0f);
                if (SCALEOUT) v *= dsc[r];
                myA[row * LROW + colc] = f2bf(v);
            }
        }
#pragma unroll
        for (int i = 0; i < 4; ++i) {
            int srow = i * 4 + (lane >> 4);
            int scol = (lane & 15) * 8;
            *(short8*)(Ob + (size_t)(row0 + srow) * 128 + scol) =
                *(const short8*)(myA + srow * LROW + scol);
        }
    } else {
        uchar* st8 = (uchar*)myA;           // byte staging, row stride 136 B
        uchar* Ob = (uchar*)Ov;
#pragma unroll
        for (int cb = 0; cb < 8; ++cb) {
            int colc = cb * 16 + m;
            float bv = bias[colc];
            float bt2 = TEMB ? bias_t[colc] : 0.f;
#pragma unroll
            for (int r = 0; r < 4; ++r) {
                int row = q * 4 + r;
                float v = fmaxf(acc[cb][r] + bv, 0.0f);
                if (TEMB) v += fmaxf(acc2[cb][r] + bt2, 0.0f);
                if (SCALEOUT) v *= dsc[r];
                int enc = __builtin_amdgcn_cvt_pk_fp8_f32(v, v, 0, false);
                st8[row * 136 + colc] = (uchar)(enc & 0xff);
            }
        }
        // 16 rows * 128 B = 2048 B; 64 lanes * 8 B = 512 B/iter -> 4 iters
#pragma unroll
        for (int i = 0; i < 4; ++i) {
            int idx = i * 64 + lane;        // [0,256)
            int srow = idx >> 4;            // [0,16)
            int soff = (idx & 15) * 8;      // [0,128) step 8
            *(uint2*)(Ob + (size_t)(row0 + srow) * 128 + soff) =
                *(const uint2*)(st8 + srow * 136 + soff);
        }
    }
}

// ---------------- pooling + output head (fused) ----------------

__global__ void pool_out(const ushort* __restrict__ h, const int* __restrict__ gstart,
                         const float* __restrict__ Wo, const float* __restrict__ bo,
                         float* __restrict__ out) {
    int g = blockIdx.x;
    int t = threadIdx.x;          // 256
    int f2 = t & 63;
    int half = t >> 6;
    int s = gstart[g], e = gstart[g + 1];
    float ax = 0.f, ay = 0.f;
    for (int i = s + half; i < e; i += 4) {
        uint u = *(const uint*)(h + (size_t)i * HID + f2 * 2);
        ax += bflo(u); ay += bfhi(u);
    }
    __shared__ float red[2][256];
    __shared__ float P[128];
    red[0][t] = ax; red[1][t] = ay;
    __syncthreads();
    if (half == 0) {
        for (int k = 1; k < 4; ++k) { ax += red[0][f2 + 64 * k]; ay += red[1][f2 + 64 * k]; }
        float c = (float)((e - s) < 1 ? 1 : (e - s));
        P[f2 * 2]     = ax / c;
        P[f2 * 2 + 1] = ay / c;
    }
    __syncthreads();
    if (t < 16) {
        float acc = bo[t];
        for (int k = 0; k < HID; ++k) acc += P[k] * Wo[k * 16 + t];
        out[g * 16 + t] = acc;
    }
}

// ---------------- launch ----------------

extern "C" void kernel_launch(void* const* d_in, const int* in_sizes, int n_in,
                              void* d_out, int out_size, void* d_ws, size_t ws_size,
                              hipStream_t stream) {
    const float* x       = (const float*)d_in[0];
    const int*   ei      = (const int*)d_in[1];
    const float* temb_in = (const float*)d_in[2];
    const int*   batch   = (const int*)d_in[3];
    const float* Wt      = (const float*)d_in[4];
    const float* bt      = (const float*)d_in[5];
    const float* W1      = (const float*)d_in[6];
    const float* b1      = (const float*)d_in[7];
    const float* Ws      = (const float*)d_in[8];
    const float* bs      = (const float*)d_in[9];
    const float* Wo      = (const float*)d_in[10];
    const float* bo      = (const float*)d_in[11];
    float* out = (float*)d_out;

    const int N = N_NODES, E = N_EDGES;
    const int* src = ei;
    const int* dst = ei + E;

    char* p = (char*)d_ws;
    auto carve = [&](size_t bytes) -> void* {
        void* r = (void*)p;
        p += (bytes + 255) & ~(size_t)255;
        return r;
    };
    int*    row_ptr    = (int*)carve((size_t)(N + 1) * 4);
    float*  dinv       = (float*)carve((size_t)N * 4);
    int*    gstart     = (int*)carve((size_t)(N_GRAPHS + 1) * 4);
    ushort* packed     = (ushort*)carve((size_t)57344 * 2);
    int*    chunk_hist = (int*)carve((size_t)NCHUNK * NB * 4);
    int*    cbase      = (int*)carve((size_t)NCHUNK * NB * 4);
    int*    bstart     = (int*)carve((size_t)(NB + 1) * 4);
    uint*   tmp        = (uint*)carve((size_t)E * 4);
    int*    edge       = (int*)carve((size_t)E * 4);
    uchar*  xb8        = (uchar*)carve((size_t)(N + 16) * 64);
    ushort* tembb      = (ushort*)carve((size_t)N * 128 * 2);
    uchar*  H1f8       = (uchar*)carve((size_t)(N + 16) * 128);
    uchar*  H2f8       = (uchar*)carve((size_t)(N + 16) * 128);
    ushort* H3         = (ushort*)carve((size_t)N * 128 * 2);

    const ushort* Wtp  = packed;
    const ushort* W1p  = packed + 16384;
    const ushort* Ws0p = packed + 24576;
    const ushort* Ws1p = packed + 40960;

    const int ntiles = N / 16;            // 6250
    const int gblk   = (ntiles + 3) / 4;  // 1563

    // prep: pack W | boundaries | cvt temb
    prep_kernel<<<3740, 256, 0, stream>>>(Wt, W1, Ws, packed, batch, gstart,
                                          temb_in, tembb);

    // CSR build v2 (bucketed counting sort; no global atomics, coalesced writes)
    hist_chunks<<<NCHUNK, 256, 0, stream>>>(dst, chunk_hist);
    scan_chunks<<<1, 256, 0, stream>>>(chunk_hist, cbase, bstart, row_ptr);
    scatter_coarse<<<NCHUNK, 256, 0, stream>>>(src, dst, cbase, tmp);
    csr_fine<<<NB, 256, 0, stream>>>(tmp, bstart, row_ptr, dinv, edge, x, xb8);

    // conv1 (+fused temb layer): H1f8 = dinv * (relu(agg(G0)@W1+b1) + relu(tembb@Wt+bt))
    fused_conv<64, true, true, true, true><<<gblk, 256, 0, stream>>>(
        xb8, row_ptr, edge, dinv, W1p, b1, tembb, Wtp, bt, H1f8, ntiles);
    // conv2 (fp8 gather, fp8 out): H2f8 = dinv * relu(agg(H1f8)@Ws0 + bs0)
    fused_conv<128, false, true, true, true><<<gblk, 256, 0, stream>>>(
        H1f8, row_ptr, edge, dinv, Ws0p, bs, nullptr, nullptr, nullptr, H2f8, ntiles);
    // conv3 (fp8 gather, bf16 out for pooling): H3 = relu(agg(H2f8)@Ws1 + bs1)
    fused_conv<128, false, true, false, false><<<gblk, 256, 0, stream>>>(
        H2f8, row_ptr, edge, dinv, Ws1p, bs + 128, nullptr, nullptr, nullptr, H3, ntiles);

    // pool + head (fused)
    pool_out<<<N_GRAPHS, 256, 0, stream>>>(H3, gstart, Wo, bo, out);
}

// Round 8
// 367.868 us; speedup vs baseline: 1.0150x; 1.0150x over previous
//
#include <hip/hip_runtime.h>

#define N_NODES  100000
#define N_EDGES  1600000
#define N_GRAPHS 512
#define HID      128
#define NB       196        // coarse buckets of 512 nodes (dst >> 9)
#define NCHUNK   196        // edge chunks of 8192
#define CHUNK    8192
#define ECAP     512        // LDS edge-span capacity per wave-tile (mean 272, 16-sigma headroom)

typedef unsigned int  uint;
typedef unsigned char uchar;
typedef unsigned short ushort;
typedef __attribute__((ext_vector_type(8))) short  short8;   // 8 bf16 (4 VGPRs)
typedef __attribute__((ext_vector_type(4))) float  f32x4;
typedef __attribute__((ext_vector_type(2))) float  f32x2;

__device__ inline float bflo(uint u) { return __uint_as_float(u << 16); }
__device__ inline float bfhi(uint u) { return __uint_as_float(u & 0xffff0000u); }
__device__ inline ushort f2bf(float f) {
    uint u = __float_as_uint(f);
    return (ushort)((u + 0x7fffu + ((u >> 16) & 1u)) >> 16);   // RNE
}
__device__ inline uint pk(float a, float b) {
    return (uint)f2bf(a) | ((uint)f2bf(b) << 16);
}

// 16-fp8 row-chunk accumulate; w in {0,1} masks OOB slots (norm folded into G = dinv*H)
__device__ inline void acc16_fp8(uint4 hv, float w, float* a) {
    f32x2 p;
    p = __builtin_amdgcn_cvt_pk_f32_fp8((int)hv.x, false); a[0]  += w * p.x; a[1]  += w * p.y;
    p = __builtin_amdgcn_cvt_pk_f32_fp8((int)hv.x, true);  a[2]  += w * p.x; a[3]  += w * p.y;
    p = __builtin_amdgcn_cvt_pk_f32_fp8((int)hv.y, false); a[4]  += w * p.x; a[5]  += w * p.y;
    p = __builtin_amdgcn_cvt_pk_f32_fp8((int)hv.y, true);  a[6]  += w * p.x; a[7]  += w * p.y;
    p = __builtin_amdgcn_cvt_pk_f32_fp8((int)hv.z, false); a[8]  += w * p.x; a[9]  += w * p.y;
    p = __builtin_amdgcn_cvt_pk_f32_fp8((int)hv.z, true);  a[10] += w * p.x; a[11] += w * p.y;
    p = __builtin_amdgcn_cvt_pk_f32_fp8((int)hv.w, false); a[12] += w * p.x; a[13] += w * p.y;
    p = __builtin_amdgcn_cvt_pk_f32_fp8((int)hv.w, true);  a[14] += w * p.x; a[15] += w * p.y;
}

// ---------------- prep: pack W | graph boundaries | cvt temb -> bf16 ----------------
// blocks: [0,224) pack, [224,615) boundary, [615,3740) temb cvt
__global__ __launch_bounds__(256)
void prep_kernel(const float* __restrict__ Wt, const float* __restrict__ W1,
                 const float* __restrict__ Ws, ushort* __restrict__ packed,
                 const int* __restrict__ batch, int* __restrict__ gstart,
                 const float* __restrict__ temb, ushort* __restrict__ tembb) {
    int b = blockIdx.x;
    int t = threadIdx.x;
    if (b < 224) {                          // pack weights into MFMA B-frag order
        int tid = b * 256 + t;
        const float* src; int p; ushort* dst;
        if (tid < 16384)      { src = Wt;         p = tid;         dst = packed; }
        else if (tid < 24576) { src = W1;         p = tid - 16384; dst = packed + 16384; }
        else if (tid < 40960) { src = Ws;         p = tid - 24576; dst = packed + 24576; }
        else                  { src = Ws + 16384; p = tid - 40960; dst = packed + 40960; }
        int j  = p & 7;
        int L  = (p >> 3) & 63;
        int cb = (p >> 9) & 7;
        int s  = p >> 12;
        int k  = s * 32 + (L >> 4) * 8 + j;
        int n  = cb * 16 + (L & 15);
        dst[p] = f2bf(src[k * 128 + n]);
    } else if (b < 615) {                   // graph boundary scan (batch sorted)
        int i = (b - 224) * 256 + t;
        if (i >= N_NODES) return;
        int bb = batch[i];
        int prev = (i == 0) ? -1 : batch[i - 1];
        for (int g = prev + 1; g <= bb; ++g) gstart[g] = i;
        if (i == N_NODES - 1) {
            for (int g = bb + 1; g <= N_GRAPHS; ++g) gstart[g] = N_NODES;
        }
    } else {                                // cvt temb (N*128 floats, 16/thread, exact)
        long i = ((long)(b - 615) * 256 + t) * 16;
#pragma unroll
        for (int k = 0; k < 4; ++k) {
            float4 f = *(const float4*)(temb + i + k * 4);
            uint2 o; o.x = pk(f.x, f.y); o.y = pk(f.z, f.w);
            *(uint2*)(tembb + i + k * 4) = o;
        }
    }
}

// ---------------- CSR build v2: 2-level bucketed counting sort ----------------

// B1: per-chunk coarse histogram (LDS only, no global atomics)
__global__ __launch_bounds__(256)
void hist_chunks(const int* __restrict__ dst, int* __restrict__ chunk_hist) {
    __shared__ int h[NB];
    int c = blockIdx.x, t = threadIdx.x;
    if (t < NB) h[t] = 0;
    __syncthreads();
    const int4* d4 = (const int4*)dst;
#pragma unroll
    for (int k = 0; k < 8; ++k) {
        int i4 = c * (CHUNK / 4) + k * 256 + t;
        if (i4 < N_EDGES / 4) {
            int4 d = d4[i4];
            atomicAdd(&h[d.x >> 9], 1);
            atomicAdd(&h[d.y >> 9], 1);
            atomicAdd(&h[d.z >> 9], 1);
            atomicAdd(&h[d.w >> 9], 1);
        }
    }
    __syncthreads();
    if (t < NB) chunk_hist[c * NB + t] = h[t];
}

// B2: single block — bucket bases + per-(chunk,bucket) bases
__global__ __launch_bounds__(256)
void scan_chunks(const int* __restrict__ chunk_hist, int* __restrict__ cbase,
                 int* __restrict__ bstart, int* __restrict__ row_ptr) {
    __shared__ int sc[256];
    int t = threadIdx.x;
    int tot = 0;
    if (t < NB)
        for (int c = 0; c < NCHUNK; ++c) tot += chunk_hist[c * NB + t];
    sc[t] = (t < NB) ? tot : 0;
    __syncthreads();
    for (int off = 1; off < 256; off <<= 1) {
        int x = (t >= off) ? sc[t - off] : 0;
        __syncthreads();
        sc[t] += x;
        __syncthreads();
    }
    int excl = sc[t] - ((t < NB) ? tot : 0);
    if (t < NB) {
        bstart[t] = excl;
        int run = excl;
        for (int c = 0; c < NCHUNK; ++c) {
            cbase[c * NB + t] = run;
            run += chunk_hist[c * NB + t];
        }
    }
    if (t == 0) { bstart[NB] = N_EDGES; row_ptr[N_NODES] = N_EDGES; }
}

// B3: per-chunk scatter into tmp — block writes contiguous runs per bucket (coalesced)
__global__ __launch_bounds__(256)
void scatter_coarse(const int* __restrict__ src, const int* __restrict__ dst,
                    const int* __restrict__ cbase, uint* __restrict__ tmp) {
    __shared__ int cur[NB];
    int c = blockIdx.x, t = threadIdx.x;
    if (t < NB) cur[t] = cbase[c * NB + t];
    __syncthreads();
    const int4* s4p = (const int4*)src;
    const int4* d4p = (const int4*)dst;
#pragma unroll
    for (int k = 0; k < 8; ++k) {
        int i4 = c * (CHUNK / 4) + k * 256 + t;
        if (i4 < N_EDGES / 4) {
            int4 s = s4p[i4];
            int4 d = d4p[i4];
            int p;
            p = atomicAdd(&cur[d.x >> 9], 1); tmp[p] = (uint)s.x | (((uint)(d.x & 511)) << 17);
            p = atomicAdd(&cur[d.y >> 9], 1); tmp[p] = (uint)s.y | (((uint)(d.y & 511)) << 17);
            p = atomicAdd(&cur[d.z >> 9], 1); tmp[p] = (uint)s.z | (((uint)(d.z & 511)) << 17);
            p = atomicAdd(&cur[d.w >> 9], 1); tmp[p] = (uint)s.w | (((uint)(d.w & 511)) << 17);
        }
    }
}

// C: one block per bucket — local hist+scan -> row_ptr/dinv, fine scatter, and fused
// xb = fp8(dinv * x)
__global__ __launch_bounds__(256)
void csr_fine(const uint* __restrict__ tmp, const int* __restrict__ bstart,
              int* __restrict__ row_ptr, float* __restrict__ dinv,
              int* __restrict__ edge, const float* __restrict__ x,
              uchar* __restrict__ xb8) {
    __shared__ int   cnt[512];
    __shared__ float dvloc[512];
    __shared__ int   ps[256];
    int b = blockIdx.x, t = threadIdx.x;
    int node0 = b << 9;
    int ncnt = min(512, N_NODES - node0);
    int s = bstart[b], e = bstart[b + 1];
    cnt[t] = 0; cnt[t + 256] = 0;
    __syncthreads();
    for (int i = s + t; i < e; i += 256) atomicAdd(&cnt[tmp[i] >> 17], 1);
    __syncthreads();
    int c0 = cnt[2 * t], c1 = cnt[2 * t + 1];
    int pair = c0 + c1;
    ps[t] = pair;
    __syncthreads();
    for (int off = 1; off < 256; off <<= 1) {
        int v = (t >= off) ? ps[t - off] : 0;
        __syncthreads();
        ps[t] += v;
        __syncthreads();
    }
    int ep = ps[t] - pair;                   // exclusive pair prefix
    int p0 = s + ep, p1 = s + ep + c0;
    float dv0 = rsqrtf((float)(c0 + 1));
    float dv1 = rsqrtf((float)(c1 + 1));
    int n0 = node0 + 2 * t;
    if (2 * t < ncnt)     { row_ptr[n0]     = p0; dinv[n0]     = dv0; }
    if (2 * t + 1 < ncnt) { row_ptr[n0 + 1] = p1; dinv[n0 + 1] = dv1; }
    dvloc[2 * t] = dv0; dvloc[2 * t + 1] = dv1;
    cnt[2 * t] = p0; cnt[2 * t + 1] = p1;    // convert counts -> absolute cursors
    __syncthreads();
    for (int i = s + t; i < e; i += 256) {
        uint rec = tmp[i];
        int p = atomicAdd(&cnt[rec >> 17], 1);
        edge[p] = (int)(rec & 0x1FFFFu);
    }
    // fused: xb8 rows for this bucket = fp8(dinv * x)  (4 feats -> 1 uint per idx)
    for (int idx = t; idx < ncnt * 16; idx += 256) {
        int row = idx >> 4, q = idx & 15;
        float4 f = ((const float4*)(x + (size_t)(node0 + row) * 64))[q];
        float d = dvloc[row];
        int w = __builtin_amdgcn_cvt_pk_fp8_f32(f.x * d, f.y * d, 0, false);
        w     = __builtin_amdgcn_cvt_pk_fp8_f32(f.z * d, f.w * d, w, true);
        *(uint*)(xb8 + (size_t)(node0 + row) * 64 + q * 4) = (uint)w;
    }
}

// ---------------- fused GCN conv ----------------
// input rows are G = dinv*H (fp8); agg_v = dinv_v * (sum_{s in N(v)} G_s + G_v)
// O = relu(agg @ W + b) [+ relu(tembb @ Wt + bt)]; SCALEOUT: store dinv*O
// Phase 1 geometry (R8): 16 fp8 bytes per lane (uint4 gathers). K=128: 8 lanes/row ->
// 8 concurrent rows, 2 serial; K=64: 4 lanes/row -> all 16 rows concurrent. Halves both
// the serial latency-chain depth and the VMEM instruction count vs R7 (which was
// latency/MLP-bound: HBM 17%, VALU 27%, Mfma 3%, occ 25% -- nothing saturated).
// Edge span staged in LDS (R7). Edge walk U=8 deep.
template <int K, bool TEMB, bool OUT8, bool SCALEOUT>
__global__ __launch_bounds__(256)
void fused_conv(const void* __restrict__ Hv, const int* __restrict__ rp,
                const int* __restrict__ edge, const float* __restrict__ dinv,
                const ushort* __restrict__ Wp, const float* __restrict__ bias,
                const ushort* __restrict__ tembb, const ushort* __restrict__ Wtp,
                const float* __restrict__ bias_t, void* __restrict__ Ov, int ntiles) {
    constexpr int LPR  = K / 16;      // lanes per row (16 fp8 feats/lane)
    constexpr int G    = 64 / LPR;    // concurrent rows (8 or 16)
    constexpr int RPG  = 16 / G;      // serial rows per group (2 or 1)
    constexpr int U    = 8;           // edge-walk unroll depth
    constexpr int LROW = 136;         // LDS row stride in shorts (bf16 staging)
    __shared__ __align__(16) ushort sA[4][16 * LROW];
    __shared__ uint sE[4][ECAP];      // per-wave edge-span stage
    const int wave = threadIdx.x >> 6;
    const int lane = threadIdx.x & 63;
    const int tile = blockIdx.x * 4 + wave;
    if (tile >= ntiles) return;       // per-wave LDS, no barriers: safe
    const int row0 = tile * 16;
    const int g  = lane / LPR;
    const int fq = lane % LPR;
    ushort* myA = sA[wave];
    const uchar* H8 = (const uchar*)Hv;

    // lane-parallel preload of row_ptr[17] / dinv[16]; broadcast via shfl
    int   rpv = rp[row0 + ((lane < 17) ? lane : 16)];
    float dvv = dinv[row0 + ((lane < 16) ? lane : 15)];

    // ---- stage the tile's contiguous edge span into LDS (coalesced) ----
    const int s0   = __shfl(rpv, 0);
    const int e15  = __shfl(rpv, 16);
    const int ecnt = e15 - s0;
    uint* sEw = sE[wave];
    for (int i = lane; i < ecnt && i < ECAP; i += 64)
        sEw[i] = ((const uint*)edge)[s0 + i];

    // ---- phase 1: each group gathers its own RPG rows (16B/lane, no reduce) ----
    auto phase1 = [&](auto eload) {
        for (int rr = 0; rr < RPG; ++rr) {
            int r = g * RPG + rr;
            int v = row0 + r;
            int s = __shfl(rpv, r), e = __shfl(rpv, r + 1);
            float a[16];
            // self-loop init: a = G_v
            {
                uint4 xv = *(const uint4*)(H8 + (size_t)v * K + fq * 16);
                f32x2 p;
                p = __builtin_amdgcn_cvt_pk_f32_fp8((int)xv.x, false); a[0]  = p.x; a[1]  = p.y;
                p = __builtin_amdgcn_cvt_pk_f32_fp8((int)xv.x, true);  a[2]  = p.x; a[3]  = p.y;
                p = __builtin_amdgcn_cvt_pk_f32_fp8((int)xv.y, false); a[4]  = p.x; a[5]  = p.y;
                p = __builtin_amdgcn_cvt_pk_f32_fp8((int)xv.y, true);  a[6]  = p.x; a[7]  = p.y;
                p = __builtin_amdgcn_cvt_pk_f32_fp8((int)xv.z, false); a[8]  = p.x; a[9]  = p.y;
                p = __builtin_amdgcn_cvt_pk_f32_fp8((int)xv.z, true);  a[10] = p.x; a[11] = p.y;
                p = __builtin_amdgcn_cvt_pk_f32_fp8((int)xv.w, false); a[12] = p.x; a[13] = p.y;
                p = __builtin_amdgcn_cvt_pk_f32_fp8((int)xv.w, true);  a[14] = p.x; a[15] = p.y;
            }
            int iters = (e - s + U - 1) / U;  // group-uniform; U-deep unrolled walk
            int j = s;
            for (int i = 0; i < iters; ++i, j += U) {
                int sv[U]; float wv[U];
#pragma unroll
                for (int u = 0; u < U; ++u) {
                    int jv = j + u;
                    int jj = (jv < e) ? jv : e - 1;   // iters>0 => e>s => e-1 valid
                    sv[u] = eload(jj);
                    wv[u] = (jv < e) ? 1.0f : 0.0f;
                }
                uint4 hv[U];
#pragma unroll
                for (int u = 0; u < U; ++u)
                    hv[u] = *(const uint4*)(H8 + (size_t)sv[u] * K + fq * 16);
#pragma unroll
                for (int u = 0; u < U; ++u) acc16_fp8(hv[u], wv[u], a);
            }
            float dv = __shfl(dvv, r);        // row-uniform scale
            uint4 o1, o2;
            o1.x = pk(a[0] * dv,  a[1] * dv);  o1.y = pk(a[2] * dv,  a[3] * dv);
            o1.z = pk(a[4] * dv,  a[5] * dv);  o1.w = pk(a[6] * dv,  a[7] * dv);
            o2.x = pk(a[8] * dv,  a[9] * dv);  o2.y = pk(a[10] * dv, a[11] * dv);
            o2.z = pk(a[12] * dv, a[13] * dv); o2.w = pk(a[14] * dv, a[15] * dv);
            *(uint4*)(myA + r * LROW + fq * 16)     = o1;
            *(uint4*)(myA + r * LROW + fq * 16 + 8) = o2;
        }
    };
    if (ecnt <= ECAP) {
        phase1([&](int jj) { return (int)sEw[jj - s0]; });       // LDS path (normal)
    } else {
        phase1([&](int jj) { return (int)((const uint*)edge)[jj]; });  // fallback
    }

    // ---- phase 2: MFMA (A from LDS, B packed from global/L2) ----
    const int m = lane & 15, q = lane >> 4;
    f32x4 acc[8];
#pragma unroll
    for (int cb = 0; cb < 8; ++cb) acc[cb] = {0.f, 0.f, 0.f, 0.f};
    constexpr int S = K / 32;
#pragma unroll
    for (int s = 0; s < S; ++s) {
        short8 av = *(const short8*)(myA + m * LROW + s * 32 + q * 8);
#pragma unroll
        for (int cb = 0; cb < 8; ++cb) {
            short8 b = *(const short8*)(Wp + (size_t)((s * 8 + cb) * 64 + lane) * 8);
            acc[cb] = __builtin_amdgcn_mfma_f32_16x16x32_bf16(av, b, acc[cb], 0, 0, 0);
        }
    }

    // ---- phase 2b (TEMB): second MFMA chain, A = prepacked bf16 temb rows ----
    f32x4 acc2[TEMB ? 8 : 1];
    if constexpr (TEMB) {
#pragma unroll
        for (int cb = 0; cb < 8; ++cb) acc2[cb] = {0.f, 0.f, 0.f, 0.f};
        const ushort* Arow = tembb + (size_t)(row0 + m) * 128 + q * 8;
#pragma unroll
        for (int s2 = 0; s2 < 4; ++s2) {
            short8 av = *(const short8*)(Arow + s2 * 32);
#pragma unroll
            for (int cb = 0; cb < 8; ++cb) {
                short8 b = *(const short8*)(Wtp + (size_t)((s2 * 8 + cb) * 64 + lane) * 8);
                acc2[cb] = __builtin_amdgcn_mfma_f32_16x16x32_bf16(av, b, acc2[cb], 0, 0, 0);
            }
        }
    }

    // ---- phase 3: epilogue into LDS, coalesced store ----
    // C/D layout: col = lane&15, row = (lane>>4)*4 + r
    float dsc[4];
    if constexpr (SCALEOUT) {
#pragma unroll
        for (int r = 0; r < 4; ++r) dsc[r] = __shfl(dvv, q * 4 + r);
    }
    if constexpr (!OUT8) {
        ushort* Ob = (ushort*)Ov;
#pragma unroll
        for (int cb = 0; cb < 8; ++cb) {
            int colc = cb * 16 + m;
            float bv = bias[colc];
            float bt2 = TEMB ? bias_t[colc] : 0.f;
#pragma unroll
            for (int r = 0; r < 4; ++r) {
                int row = q * 4 + r;
                float v = fmaxf(acc[cb][r] + bv, 0.0f);
                if (TEMB) v += fmaxf(acc2[cb][r] + bt2, 0.0f);
                if (SCALEOUT) v *= dsc[r];
                myA[row * LROW + colc] = f2bf(v);
            }
        }
#pragma unroll
        for (int i = 0; i < 4; ++i) {
            int srow = i * 4 + (lane >> 4);
            int scol = (lane & 15) * 8;
            *(short8*)(Ob + (size_t)(row0 + srow) * 128 + scol) =
                *(const short8*)(myA + srow * LROW + scol);
        }
    } else {
        uchar* st8 = (uchar*)myA;           // byte staging, row stride 136 B
        uchar* Ob = (uchar*)Ov;
#pragma unroll
        for (int cb = 0; cb < 8; ++cb) {
            int colc = cb * 16 + m;
            float bv = bias[colc];
            float bt2 = TEMB ? bias_t[colc] : 0.f;
#pragma unroll
            for (int r = 0; r < 4; ++r) {
                int row = q * 4 + r;
                float v = fmaxf(acc[cb][r] + bv, 0.0f);
                if (TEMB) v += fmaxf(acc2[cb][r] + bt2, 0.0f);
                if (SCALEOUT) v *= dsc[r];
                int enc = __builtin_amdgcn_cvt_pk_fp8_f32(v, v, 0, false);
                st8[row * 136 + colc] = (uchar)(enc & 0xff);
            }
        }
        // 16 rows * 128 B = 2048 B; 64 lanes * 8 B = 512 B/iter -> 4 iters
#pragma unroll
        for (int i = 0; i < 4; ++i) {
            int idx = i * 64 + lane;        // [0,256)
            int srow = idx >> 4;            // [0,16)
            int soff = (idx & 15) * 8;      // [0,128) step 8
            *(uint2*)(Ob + (size_t)(row0 + srow) * 128 + soff) =
                *(const uint2*)(st8 + srow * 136 + soff);
        }
    }
}

// ---------------- pooling + output head (fused) ----------------

__global__ void pool_out(const ushort* __restrict__ h, const int* __restrict__ gstart,
                         const float* __restrict__ Wo, const float* __restrict__ bo,
                         float* __restrict__ out) {
    int g = blockIdx.x;
    int t = threadIdx.x;          // 256
    int f4 = t & 31;              // feat quad: feats f4*4 .. f4*4+3
    int sl = t >> 5;              // 8 node slices
    int s = gstart[g], e = gstart[g + 1];
    float a0 = 0.f, a1 = 0.f, a2 = 0.f, a3 = 0.f;
    for (int i = s + sl; i < e; i += 8) {
        uint2 u = *(const uint2*)(h + (size_t)i * HID + f4 * 4);
        a0 += bflo(u.x); a1 += bfhi(u.x);
        a2 += bflo(u.y); a3 += bfhi(u.y);
    }
    __shared__ float red[256][4];
    __shared__ float P[128];
    red[t][0] = a0; red[t][1] = a1; red[t][2] = a2; red[t][3] = a3;
    __syncthreads();
    if (sl == 0) {
        for (int k = 1; k < 8; ++k) {
            a0 += red[f4 + 32 * k][0]; a1 += red[f4 + 32 * k][1];
            a2 += red[f4 + 32 * k][2]; a3 += red[f4 + 32 * k][3];
        }
        float c = (float)((e - s) < 1 ? 1 : (e - s));
        P[f4 * 4]     = a0 / c; P[f4 * 4 + 1] = a1 / c;
        P[f4 * 4 + 2] = a2 / c; P[f4 * 4 + 3] = a3 / c;
    }
    __syncthreads();
    if (t < 16) {
        float acc = bo[t];
        for (int k = 0; k < HID; ++k) acc += P[k] * Wo[k * 16 + t];
        out[g * 16 + t] = acc;
    }
}

// ---------------- launch ----------------

extern "C" void kernel_launch(void* const* d_in, const int* in_sizes, int n_in,
                              void* d_out, int out_size, void* d_ws, size_t ws_size,
                              hipStream_t stream) {
    const float* x       = (const float*)d_in[0];
    const int*   ei      = (const int*)d_in[1];
    const float* temb_in = (const float*)d_in[2];
    const int*   batch   = (const int*)d_in[3];
    const float* Wt      = (const float*)d_in[4];
    const float* bt      = (const float*)d_in[5];
    const float* W1      = (const float*)d_in[6];
    const float* b1      = (const float*)d_in[7];
    const float* Ws      = (const float*)d_in[8];
    const float* bs      = (const float*)d_in[9];
    const float* Wo      = (const float*)d_in[10];
    const float* bo      = (const float*)d_in[11];
    float* out = (float*)d_out;

    const int N = N_NODES, E = N_EDGES;
    const int* src = ei;
    const int* dst = ei + E;

    char* p = (char*)d_ws;
    auto carve = [&](size_t bytes) -> void* {
        void* r = (void*)p;
        p += (bytes + 255) & ~(size_t)255;
        return r;
    };
    int*    row_ptr    = (int*)carve((size_t)(N + 1) * 4);
    float*  dinv       = (float*)carve((size_t)N * 4);
    int*    gstart     = (int*)carve((size_t)(N_GRAPHS + 1) * 4);
    ushort* packed     = (ushort*)carve((size_t)57344 * 2);
    int*    chunk_hist = (int*)carve((size_t)NCHUNK * NB * 4);
    int*    cbase      = (int*)carve((size_t)NCHUNK * NB * 4);
    int*    bstart     = (int*)carve((size_t)(NB + 1) * 4);
    uint*   tmp        = (uint*)carve((size_t)E * 4);
    int*    edge       = (int*)carve((size_t)E * 4);
    uchar*  xb8        = (uchar*)carve((size_t)(N + 16) * 64);
    ushort* tembb      = (ushort*)carve((size_t)N * 128 * 2);
    uchar*  H1f8       = (uchar*)carve((size_t)(N + 16) * 128);
    uchar*  H2f8       = (uchar*)carve((size_t)(N + 16) * 128);
    ushort* H3         = (ushort*)carve((size_t)N * 128 * 2);

    const ushort* Wtp  = packed;
    const ushort* W1p  = packed + 16384;
    const ushort* Ws0p = packed + 24576;
    const ushort* Ws1p = packed + 40960;

    const int ntiles = N / 16;            // 6250
    const int gblk   = (ntiles + 3) / 4;  // 1563

    // prep: pack W | boundaries | cvt temb
    prep_kernel<<<3740, 256, 0, stream>>>(Wt, W1, Ws, packed, batch, gstart,
                                          temb_in, tembb);

    // CSR build v2 (bucketed counting sort; no global atomics, coalesced writes)
    hist_chunks<<<NCHUNK, 256, 0, stream>>>(dst, chunk_hist);
    scan_chunks<<<1, 256, 0, stream>>>(chunk_hist, cbase, bstart, row_ptr);
    scatter_coarse<<<NCHUNK, 256, 0, stream>>>(src, dst, cbase, tmp);
    csr_fine<<<NB, 256, 0, stream>>>(tmp, bstart, row_ptr, dinv, edge, x, xb8);

    // conv1 (+fused temb layer): H1f8 = dinv * (relu(agg(G0)@W1+b1) + relu(tembb@Wt+bt))
    fused_conv<64, true, true, true><<<gblk, 256, 0, stream>>>(
        xb8, row_ptr, edge, dinv, W1p, b1, tembb, Wtp, bt, H1f8, ntiles);
    // conv2 (fp8 gather, fp8 out): H2f8 = dinv * relu(agg(H1f8)@Ws0 + bs0)
    fused_conv<128, false, true, true><<<gblk, 256, 0, stream>>>(
        H1f8, row_ptr, edge, dinv, Ws0p, bs, nullptr, nullptr, nullptr, H2f8, ntiles);
    // conv3 (fp8 gather, bf16 out for pooling): H3 = relu(agg(H2f8)@Ws1 + bs1)
    fused_conv<128, false, false, false><<<gblk, 256, 0, stream>>>(
        H2f8, row_ptr, edge, dinv, Ws1p, bs + 128, nullptr, nullptr, nullptr, H3, ntiles);

    // pool + head (fused)
    pool_out<<<N_GRAPHS, 256, 0, stream>>>(H3, gstart, Wo, bo, out);
}

// Round 10
// 347.140 us; speedup vs baseline: 1.0756x; 1.0597x over previous
//
#include <hip/hip_runtime.h>

#define N_NODES  100000
#define N_EDGES  1600000
#define N_GRAPHS 512
#define HID      128
#define NB       782        // fine buckets of 128 nodes (dst >> 7)
#define NCHUNK   196        // edge chunks of 8192
#define CHUNK    8192
#define ECAP     512        // LDS edge-span capacity per wave-tile (mean 272, 16-sigma headroom)

typedef unsigned int  uint;
typedef unsigned char uchar;
typedef unsigned short ushort;
typedef __attribute__((ext_vector_type(8))) short  short8;   // 8 bf16 (4 VGPRs)
typedef __attribute__((ext_vector_type(4))) float  f32x4;
typedef __attribute__((ext_vector_type(2))) float  f32x2;

__device__ inline float bflo(uint u) { return __uint_as_float(u << 16); }
__device__ inline float bfhi(uint u) { return __uint_as_float(u & 0xffff0000u); }
__device__ inline ushort f2bf(float f) {
    uint u = __float_as_uint(f);
    return (ushort)((u + 0x7fffu + ((u >> 16) & 1u)) >> 16);   // RNE
}
__device__ inline uint pk(float a, float b) {
    return (uint)f2bf(a) | ((uint)f2bf(b) << 16);
}

// 16-fp8 row-chunk accumulate; w in {0,1} masks OOB slots (norm folded into G = dinv*H)
__device__ inline void acc16_fp8(uint4 hv, float w, float* a) {
    f32x2 p;
    p = __builtin_amdgcn_cvt_pk_f32_fp8((int)hv.x, false); a[0]  += w * p.x; a[1]  += w * p.y;
    p = __builtin_amdgcn_cvt_pk_f32_fp8((int)hv.x, true);  a[2]  += w * p.x; a[3]  += w * p.y;
    p = __builtin_amdgcn_cvt_pk_f32_fp8((int)hv.y, false); a[4]  += w * p.x; a[5]  += w * p.y;
    p = __builtin_amdgcn_cvt_pk_f32_fp8((int)hv.y, true);  a[6]  += w * p.x; a[7]  += w * p.y;
    p = __builtin_amdgcn_cvt_pk_f32_fp8((int)hv.z, false); a[8]  += w * p.x; a[9]  += w * p.y;
    p = __builtin_amdgcn_cvt_pk_f32_fp8((int)hv.z, true);  a[10] += w * p.x; a[11] += w * p.y;
    p = __builtin_amdgcn_cvt_pk_f32_fp8((int)hv.w, false); a[12] += w * p.x; a[13] += w * p.y;
    p = __builtin_amdgcn_cvt_pk_f32_fp8((int)hv.w, true);  a[14] += w * p.x; a[15] += w * p.y;
}

// ---------------- prep: pack W | boundaries | cvt temb | coarse hist | zero pooled ----
// blocks: [0,224) pack, [224,615) boundary, [615,3740) temb, [3740,3936) hist,
//         [3936,4192) pooled zero
__global__ __launch_bounds__(256)
void prep_kernel(const float* __restrict__ Wt, const float* __restrict__ W1,
                 const float* __restrict__ Ws, ushort* __restrict__ packed,
                 const int* __restrict__ batch, int* __restrict__ gstart,
                 const float* __restrict__ temb, ushort* __restrict__ tembb,
                 const int* __restrict__ dst, int* __restrict__ chunk_hist,
                 float* __restrict__ pooled) {
    __shared__ int h[NB];
    int b = blockIdx.x;
    int t = threadIdx.x;
    if (b < 224) {                          // pack weights into MFMA B-frag order
        int tid = b * 256 + t;
        const float* src; int p; ushort* dstp;
        if (tid < 16384)      { src = Wt;         p = tid;         dstp = packed; }
        else if (tid < 24576) { src = W1;         p = tid - 16384; dstp = packed + 16384; }
        else if (tid < 40960) { src = Ws;         p = tid - 24576; dstp = packed + 24576; }
        else                  { src = Ws + 16384; p = tid - 40960; dstp = packed + 40960; }
        int j  = p & 7;
        int L  = (p >> 3) & 63;
        int cb = (p >> 9) & 7;
        int s  = p >> 12;
        int k  = s * 32 + (L >> 4) * 8 + j;
        int n  = cb * 16 + (L & 15);
        dstp[p] = f2bf(src[k * 128 + n]);
    } else if (b < 615) {                   // graph boundary scan (batch sorted)
        int i = (b - 224) * 256 + t;
        if (i >= N_NODES) return;
        int bb = batch[i];
        int prev = (i == 0) ? -1 : batch[i - 1];
        for (int g = prev + 1; g <= bb; ++g) gstart[g] = i;
        if (i == N_NODES - 1) {
            for (int g = bb + 1; g <= N_GRAPHS; ++g) gstart[g] = N_NODES;
        }
    } else if (b < 3740) {                  // cvt temb (N*128 floats, 16/thread, exact)
        long i = ((long)(b - 615) * 256 + t) * 16;
#pragma unroll
        for (int k = 0; k < 4; ++k) {
            float4 f = *(const float4*)(temb + i + k * 4);
            uint2 o; o.x = pk(f.x, f.y); o.y = pk(f.z, f.w);
            *(uint2*)(tembb + i + k * 4) = o;
        }
    } else if (b < 3936) {                  // coarse histogram per chunk (LDS only)
        int c = b - 3740;
        for (int i = t; i < NB; i += 256) h[i] = 0;
        __syncthreads();
        const int4* d4 = (const int4*)dst;
#pragma unroll
        for (int k = 0; k < 8; ++k) {
            int i4 = c * (CHUNK / 4) + k * 256 + t;
            if (i4 < N_EDGES / 4) {
                int4 d = d4[i4];
                atomicAdd(&h[d.x >> 7], 1);
                atomicAdd(&h[d.y >> 7], 1);
                atomicAdd(&h[d.z >> 7], 1);
                atomicAdd(&h[d.w >> 7], 1);
            }
        }
        __syncthreads();
        for (int i = t; i < NB; i += 256) chunk_hist[c * NB + i] = h[i];
    } else {                                // zero pooled accumulators (512*128)
        pooled[(b - 3936) * 256 + t] = 0.f;
    }
}

// ---------------- CSR build v3: parallel bucketed counting sort ----------------

// scanA: one block per bucket — prefix over chunks (transposed cbaseT for coalescing)
__global__ __launch_bounds__(256)
void scanA(const int* __restrict__ chunk_hist, int* __restrict__ cbaseT,
           int* __restrict__ btotal) {
    __shared__ int sc[256];
    int b = blockIdx.x, t = threadIdx.x;
    int v = (t < NCHUNK) ? chunk_hist[t * NB + b] : 0;
    sc[t] = v;
    __syncthreads();
    for (int off = 1; off < 256; off <<= 1) {
        int x = (t >= off) ? sc[t - off] : 0;
        __syncthreads();
        sc[t] += x;
        __syncthreads();
    }
    if (t < NCHUNK) cbaseT[b * NCHUNK + t] = sc[t] - v;   // excl prefix, pre-bstart
    if (t == 255) btotal[b] = sc[255];
}

// scanB: single tiny block — exclusive scan of 782 bucket totals
__global__ __launch_bounds__(256)
void scanB(const int* __restrict__ btotal, int* __restrict__ bstart,
           int* __restrict__ row_ptr) {
    __shared__ int sc[256];
    int t = threadIdx.x;
    int v[4]; int sum = 0;
#pragma unroll
    for (int k = 0; k < 4; ++k) {
        int idx = t * 4 + k;
        v[k] = (idx < NB) ? btotal[idx] : 0;
        sum += v[k];
    }
    sc[t] = sum;
    __syncthreads();
    for (int off = 1; off < 256; off <<= 1) {
        int x = (t >= off) ? sc[t - off] : 0;
        __syncthreads();
        sc[t] += x;
        __syncthreads();
    }
    int run = sc[t] - sum;
#pragma unroll
    for (int k = 0; k < 4; ++k) {
        int idx = t * 4 + k;
        if (idx < NB) bstart[idx] = run;
        run += v[k];
    }
    if (t == 0) { bstart[NB] = N_EDGES; row_ptr[N_NODES] = N_EDGES; }
}

// scatter: per-chunk into tmp — contiguous runs per bucket (bases = cbaseT + bstart)
__global__ __launch_bounds__(256)
void scatter_coarse(const int* __restrict__ src, const int* __restrict__ dst,
                    const int* __restrict__ cbaseT, const int* __restrict__ bstart,
                    uint* __restrict__ tmp) {
    __shared__ int cur[NB];
    int c = blockIdx.x, t = threadIdx.x;
    for (int i = t; i < NB; i += 256) cur[i] = cbaseT[i * NCHUNK + c] + bstart[i];
    __syncthreads();
    const int4* s4p = (const int4*)src;
    const int4* d4p = (const int4*)dst;
#pragma unroll
    for (int k = 0; k < 8; ++k) {
        int i4 = c * (CHUNK / 4) + k * 256 + t;
        if (i4 < N_EDGES / 4) {
            int4 s = s4p[i4];
            int4 d = d4p[i4];
            int p;
            p = atomicAdd(&cur[d.x >> 7], 1); tmp[p] = (uint)s.x | (((uint)(d.x & 127)) << 17);
            p = atomicAdd(&cur[d.y >> 7], 1); tmp[p] = (uint)s.y | (((uint)(d.y & 127)) << 17);
            p = atomicAdd(&cur[d.z >> 7], 1); tmp[p] = (uint)s.z | (((uint)(d.z & 127)) << 17);
            p = atomicAdd(&cur[d.w >> 7], 1); tmp[p] = (uint)s.w | (((uint)(d.w & 127)) << 17);
        }
    }
}

// csr_fine: one block per 128-node bucket (782 blocks, 3/CU) — local hist+scan ->
// row_ptr/dinv, fine scatter, fused xb8 = fp8(dinv * x)
__global__ __launch_bounds__(256)
void csr_fine(const uint* __restrict__ tmp, const int* __restrict__ bstart,
              int* __restrict__ row_ptr, float* __restrict__ dinv,
              int* __restrict__ edge, const float* __restrict__ x,
              uchar* __restrict__ xb8) {
    __shared__ int   cnt[128];
    __shared__ float dvloc[128];
    __shared__ int   ps[128];
    int b = blockIdx.x, t = threadIdx.x;
    int node0 = b << 7;
    int ncnt = min(128, N_NODES - node0);
    int s = bstart[b], e = bstart[b + 1];
    if (t < 128) cnt[t] = 0;
    __syncthreads();
    for (int i = s + t; i < e; i += 256) atomicAdd(&cnt[tmp[i] >> 17], 1);
    __syncthreads();
    int c0 = (t < 128) ? cnt[t] : 0;
    if (t < 128) ps[t] = c0;
    __syncthreads();
    for (int off = 1; off < 128; off <<= 1) {
        int v = (t < 128 && t >= off) ? ps[t - off] : 0;
        __syncthreads();
        if (t < 128) ps[t] += v;
        __syncthreads();
    }
    if (t < 128) {
        int p0 = s + ps[t] - c0;
        float dv = rsqrtf((float)(c0 + 1));
        if (t < ncnt) { row_ptr[node0 + t] = p0; dinv[node0 + t] = dv; }
        dvloc[t] = dv;
        cnt[t] = p0;                         // counts -> absolute cursors
    }
    __syncthreads();
    for (int i = s + t; i < e; i += 256) {
        uint rec = tmp[i];
        int p = atomicAdd(&cnt[rec >> 17], 1);
        edge[p] = (int)(rec & 0x1FFFFu);
    }
    // fused: xb8 rows for this bucket = fp8(dinv * x)  (4 feats -> 1 uint per idx)
    for (int idx = t; idx < ncnt * 16; idx += 256) {
        int row = idx >> 4, q = idx & 15;
        float4 f = ((const float4*)(x + (size_t)(node0 + row) * 64))[q];
        float d = dvloc[row];
        int w = __builtin_amdgcn_cvt_pk_fp8_f32(f.x * d, f.y * d, 0, false);
        w     = __builtin_amdgcn_cvt_pk_fp8_f32(f.z * d, f.w * d, w, true);
        *(uint*)(xb8 + (size_t)(node0 + row) * 64 + q * 4) = (uint)w;
    }
}

// ---------------- fused GCN conv ----------------
// input rows are G = dinv*H (fp8); agg_v = dinv_v * (sum_{s in N(v)} G_s + G_v)
// O = relu(agg @ W + b) [+ relu(tembb @ Wt + bt)]; SCALEOUT: store dinv*O
// POOL: no per-node output — per-tile per-graph partial sums atomically added into
// pooled[512][128] (batch sorted -> segment flush); kills H3 (51 MB round trip) + pool kernel.
template <int K, bool TEMB, bool OUT8, bool SCALEOUT, bool POOL>
__global__ __launch_bounds__(256)
void fused_conv(const void* __restrict__ Hv, const int* __restrict__ rp,
                const int* __restrict__ edge, const float* __restrict__ dinv,
                const ushort* __restrict__ Wp, const float* __restrict__ bias,
                const ushort* __restrict__ tembb, const ushort* __restrict__ Wtp,
                const float* __restrict__ bias_t, void* __restrict__ Ov,
                const int* __restrict__ batchp, float* __restrict__ pooled, int ntiles) {
    constexpr int LPR  = K / 16;      // lanes per row (16 fp8 feats/lane)
    constexpr int G    = 64 / LPR;    // concurrent rows (8 or 16)
    constexpr int RPG  = 16 / G;      // serial rows per group (2 or 1)
    constexpr int U    = 8;           // edge-walk unroll depth
    constexpr int LROW = 136;         // LDS row stride in shorts (bf16 staging)
    __shared__ __align__(16) ushort sA[4][16 * LROW];
    __shared__ uint sE[4][ECAP];      // per-wave edge-span stage
    const int wave = threadIdx.x >> 6;
    const int lane = threadIdx.x & 63;
    const int tile = blockIdx.x * 4 + wave;
    if (tile >= ntiles) return;       // per-wave LDS, no barriers: safe
    const int row0 = tile * 16;
    const int g  = lane / LPR;
    const int fq = lane % LPR;
    ushort* myA = sA[wave];
    const uchar* H8 = (const uchar*)Hv;

    // lane-parallel preload of row_ptr[17] / dinv[16]; broadcast via shfl
    int   rpv = rp[row0 + ((lane < 17) ? lane : 16)];
    float dvv = dinv[row0 + ((lane < 16) ? lane : 15)];

    // ---- stage the tile's contiguous edge span into LDS (coalesced) ----
    const int s0   = __shfl(rpv, 0);
    const int e15  = __shfl(rpv, 16);
    const int ecnt = e15 - s0;
    uint* sEw = sE[wave];
    for (int i = lane; i < ecnt && i < ECAP; i += 64)
        sEw[i] = ((const uint*)edge)[s0 + i];

    // ---- phase 1: each group gathers its own RPG rows (16B/lane, no reduce) ----
    auto phase1 = [&](auto eload) {
        for (int rr = 0; rr < RPG; ++rr) {
            int r = g * RPG + rr;
            int v = row0 + r;
            int s = __shfl(rpv, r), e = __shfl(rpv, r + 1);
            float a[16];
            // self-loop init: a = G_v
            {
                uint4 xv = *(const uint4*)(H8 + (size_t)v * K + fq * 16);
                f32x2 p;
                p = __builtin_amdgcn_cvt_pk_f32_fp8((int)xv.x, false); a[0]  = p.x; a[1]  = p.y;
                p = __builtin_amdgcn_cvt_pk_f32_fp8((int)xv.x, true);  a[2]  = p.x; a[3]  = p.y;
                p = __builtin_amdgcn_cvt_pk_f32_fp8((int)xv.y, false); a[4]  = p.x; a[5]  = p.y;
                p = __builtin_amdgcn_cvt_pk_f32_fp8((int)xv.y, true);  a[6]  = p.x; a[7]  = p.y;
                p = __builtin_amdgcn_cvt_pk_f32_fp8((int)xv.z, false); a[8]  = p.x; a[9]  = p.y;
                p = __builtin_amdgcn_cvt_pk_f32_fp8((int)xv.z, true);  a[10] = p.x; a[11] = p.y;
                p = __builtin_amdgcn_cvt_pk_f32_fp8((int)xv.w, false); a[12] = p.x; a[13] = p.y;
                p = __builtin_amdgcn_cvt_pk_f32_fp8((int)xv.w, true);  a[14] = p.x; a[15] = p.y;
            }
            int iters = (e - s + U - 1) / U;  // group-uniform; U-deep unrolled walk
            int j = s;
            for (int i = 0; i < iters; ++i, j += U) {
                int sv[U];
#pragma unroll
                for (int u = 0; u < U; ++u) {
                    int jv = j + u;
                    int jj = (jv < e) ? jv : e - 1;   // iters>0 => e>s => e-1 valid
                    sv[u] = eload(jj);
                }
                uint4 hv[U];
#pragma unroll
                for (int u = 0; u < U; ++u)
                    hv[u] = *(const uint4*)(H8 + (size_t)sv[u] * K + fq * 16);
#pragma unroll
                for (int u = 0; u < U; ++u) {
                    float w = (j + u < e) ? 1.0f : 0.0f;   // recompute mask (no wv[])
                    acc16_fp8(hv[u], w, a);
                }
            }
            float dv = __shfl(dvv, r);        // row-uniform scale
            uint4 o1, o2;
            o1.x = pk(a[0] * dv,  a[1] * dv);  o1.y = pk(a[2] * dv,  a[3] * dv);
            o1.z = pk(a[4] * dv,  a[5] * dv);  o1.w = pk(a[6] * dv,  a[7] * dv);
            o2.x = pk(a[8] * dv,  a[9] * dv);  o2.y = pk(a[10] * dv, a[11] * dv);
            o2.z = pk(a[12] * dv, a[13] * dv); o2.w = pk(a[14] * dv, a[15] * dv);
            *(uint4*)(myA + r * LROW + fq * 16)     = o1;
            *(uint4*)(myA + r * LROW + fq * 16 + 8) = o2;
        }
    };
    if (ecnt <= ECAP) {
        phase1([&](int jj) { return (int)sEw[jj - s0]; });       // LDS path (normal)
    } else {
        phase1([&](int jj) { return (int)((const uint*)edge)[jj]; });  // fallback
    }

    // ---- phase 2: MFMA (A from LDS, B packed from global/L2) ----
    const int m = lane & 15, q = lane >> 4;
    f32x4 acc[8];
#pragma unroll
    for (int cb = 0; cb < 8; ++cb) acc[cb] = {0.f, 0.f, 0.f, 0.f};
    constexpr int S = K / 32;
#pragma unroll
    for (int s = 0; s < S; ++s) {
        short8 av = *(const short8*)(myA + m * LROW + s * 32 + q * 8);
#pragma unroll
        for (int cb = 0; cb < 8; ++cb) {
            short8 b = *(const short8*)(Wp + (size_t)((s * 8 + cb) * 64 + lane) * 8);
            acc[cb] = __builtin_amdgcn_mfma_f32_16x16x32_bf16(av, b, acc[cb], 0, 0, 0);
        }
    }

    // ---- phase 2b (TEMB): second MFMA chain, A = prepacked bf16 temb rows ----
    f32x4 acc2[TEMB ? 8 : 1];
    if constexpr (TEMB) {
#pragma unroll
        for (int cb = 0; cb < 8; ++cb) acc2[cb] = {0.f, 0.f, 0.f, 0.f};
        const ushort* Arow = tembb + (size_t)(row0 + m) * 128 + q * 8;
#pragma unroll
        for (int s2 = 0; s2 < 4; ++s2) {
            short8 av = *(const short8*)(Arow + s2 * 32);
#pragma unroll
            for (int cb = 0; cb < 8; ++cb) {
                short8 b = *(const short8*)(Wtp + (size_t)((s2 * 8 + cb) * 64 + lane) * 8);
                acc2[cb] = __builtin_amdgcn_mfma_f32_16x16x32_bf16(av, b, acc2[cb], 0, 0, 0);
            }
        }
    }

    // ---- phase 3: epilogue into LDS staging, then store / pool ----
    // C/D layout: col = lane&15, row = (lane>>4)*4 + r
    float dsc[4];
    if constexpr (SCALEOUT) {
#pragma unroll
        for (int r = 0; r < 4; ++r) dsc[r] = __shfl(dvv, q * 4 + r);
    }
    if constexpr (!OUT8) {
        ushort* Ob = (ushort*)Ov;
#pragma unroll
        for (int cb = 0; cb < 8; ++cb) {
            int colc = cb * 16 + m;
            float bv = bias[colc];
            float bt2 = TEMB ? bias_t[colc] : 0.f;
#pragma unroll
            for (int r = 0; r < 4; ++r) {
                int row = q * 4 + r;
                float v = fmaxf(acc[cb][r] + bv, 0.0f);
                if (TEMB) v += fmaxf(acc2[cb][r] + bt2, 0.0f);
                if (SCALEOUT) v *= dsc[r];
                myA[row * LROW + colc] = f2bf(v);
            }
        }
        if constexpr (!POOL) {
#pragma unroll
            for (int i = 0; i < 4; ++i) {
                int srow = i * 4 + (lane >> 4);
                int scol = (lane & 15) * 8;
                *(short8*)(Ob + (size_t)(row0 + srow) * 128 + scol) =
                    *(const short8*)(myA + srow * LROW + scol);
            }
        } else {
            // per-graph segment sums over the 16 rows (batch sorted), 2 cols/lane
            int gidv = (lane < 16) ? batchp[row0 + lane] : 0;
            int colb = lane * 2;
            float p0 = 0.f, p1 = 0.f;
#pragma unroll
            for (int r = 0; r < 16; ++r) {
                uint u = *(const uint*)(myA + r * LROW + colb);
                p0 += bflo(u); p1 += bfhi(u);
                int curg  = __shfl(gidv, r);
                int nextg = (r < 15) ? __shfl(gidv, r + 1) : -1;
                if (nextg != curg) {
                    atomicAdd(&pooled[curg * 128 + colb],     p0);
                    atomicAdd(&pooled[curg * 128 + colb + 1], p1);
                    p0 = 0.f; p1 = 0.f;
                }
            }
        }
    } else {
        uchar* st8 = (uchar*)myA;           // byte staging, row stride 136 B
        uchar* Ob = (uchar*)Ov;
#pragma unroll
        for (int cb = 0; cb < 8; ++cb) {
            int colc = cb * 16 + m;
            float bv = bias[colc];
            float bt2 = TEMB ? bias_t[colc] : 0.f;
#pragma unroll
            for (int r = 0; r < 4; ++r) {
                int row = q * 4 + r;
                float v = fmaxf(acc[cb][r] + bv, 0.0f);
                if (TEMB) v += fmaxf(acc2[cb][r] + bt2, 0.0f);
                if (SCALEOUT) v *= dsc[r];
                int enc = __builtin_amdgcn_cvt_pk_fp8_f32(v, v, 0, false);
                st8[row * 136 + colc] = (uchar)(enc & 0xff);
            }
        }
        // 16 rows * 128 B = 2048 B; 64 lanes * 8 B = 512 B/iter -> 4 iters
#pragma unroll
        for (int i = 0; i < 4; ++i) {
            int idx = i * 64 + lane;        // [0,256)
            int srow = idx >> 4;            // [0,16)
            int soff = (idx & 15) * 8;      // [0,128) step 8
            *(uint2*)(Ob + (size_t)(row0 + srow) * 128 + soff) =
                *(const uint2*)(st8 + srow * 136 + soff);
        }
    }
}

// ---------------- output head: out[g] = (pooled[g]/cnt) @ Wo + bo ----------------

__global__ __launch_bounds__(256)
void head_kernel(const float* __restrict__ pooled, const int* __restrict__ gstart,
                 const float* __restrict__ Wo, const float* __restrict__ bo,
                 float* __restrict__ out) {
    int g  = blockIdx.x * 16 + (threadIdx.x >> 4);
    int tg = threadIdx.x & 15;
    if (g >= N_GRAPHS) return;
    int c = gstart[g + 1] - gstart[g];
    float inv = 1.0f / (float)(c < 1 ? 1 : c);
    float acc = bo[tg];
    for (int k = 0; k < HID; ++k)
        acc += pooled[g * 128 + k] * inv * Wo[k * 16 + tg];
    out[g * 16 + tg] = acc;
}

// ---------------- launch ----------------

extern "C" void kernel_launch(void* const* d_in, const int* in_sizes, int n_in,
                              void* d_out, int out_size, void* d_ws, size_t ws_size,
                              hipStream_t stream) {
    const float* x       = (const float*)d_in[0];
    const int*   ei      = (const int*)d_in[1];
    const float* temb_in = (const float*)d_in[2];
    const int*   batch   = (const int*)d_in[3];
    const float* Wt      = (const float*)d_in[4];
    const float* bt      = (const float*)d_in[5];
    const float* W1      = (const float*)d_in[6];
    const float* b1      = (const float*)d_in[7];
    const float* Ws      = (const float*)d_in[8];
    const float* bs      = (const float*)d_in[9];
    const float* Wo      = (const float*)d_in[10];
    const float* bo      = (const float*)d_in[11];
    float* out = (float*)d_out;

    const int N = N_NODES, E = N_EDGES;
    const int* src = ei;
    const int* dst = ei + E;

    char* p = (char*)d_ws;
    auto carve = [&](size_t bytes) -> void* {
        void* r = (void*)p;
        p += (bytes + 255) & ~(size_t)255;
        return r;
    };
    int*    row_ptr    = (int*)carve((size_t)(N + 1) * 4);
    float*  dinv       = (float*)carve((size_t)N * 4);
    int*    gstart     = (int*)carve((size_t)(N_GRAPHS + 1) * 4);
    ushort* packed     = (ushort*)carve((size_t)57344 * 2);
    int*    chunk_hist = (int*)carve((size_t)NCHUNK * NB * 4);
    int*    cbaseT     = (int*)carve((size_t)NB * NCHUNK * 4);
    int*    btotal     = (int*)carve((size_t)NB * 4);
    int*    bstart     = (int*)carve((size_t)(NB + 1) * 4);
    uint*   tmp        = (uint*)carve((size_t)E * 4);
    int*    edge       = (int*)carve((size_t)E * 4);
    uchar*  xb8        = (uchar*)carve((size_t)(N + 16) * 64);
    ushort* tembb      = (ushort*)carve((size_t)N * 128 * 2);
    uchar*  H1f8       = (uchar*)carve((size_t)(N + 16) * 128);
    uchar*  H2f8       = (uchar*)carve((size_t)(N + 16) * 128);
    float*  pooled     = (float*)carve((size_t)N_GRAPHS * 128 * 4);

    const ushort* Wtp  = packed;
    const ushort* W1p  = packed + 16384;
    const ushort* Ws0p = packed + 24576;
    const ushort* Ws1p = packed + 40960;

    const int ntiles = N / 16;            // 6250
    const int gblk   = (ntiles + 3) / 4;  // 1563

    // prep: pack W | boundaries | cvt temb | coarse hist | zero pooled
    prep_kernel<<<4192, 256, 0, stream>>>(Wt, W1, Ws, packed, batch, gstart,
                                          temb_in, tembb, dst, chunk_hist, pooled);

    // CSR build v3 (parallel scans; 782 fine buckets of 128 nodes)
    scanA<<<NB, 256, 0, stream>>>(chunk_hist, cbaseT, btotal);
    scanB<<<1, 256, 0, stream>>>(btotal, bstart, row_ptr);
    scatter_coarse<<<NCHUNK, 256, 0, stream>>>(src, dst, cbaseT, bstart, tmp);
    csr_fine<<<NB, 256, 0, stream>>>(tmp, bstart, row_ptr, dinv, edge, x, xb8);

    // conv1 (+fused temb layer): H1f8 = dinv * (relu(agg(G0)@W1+b1) + relu(tembb@Wt+bt))
    fused_conv<64, true, true, true, false><<<gblk, 256, 0, stream>>>(
        xb8, row_ptr, edge, dinv, W1p, b1, tembb, Wtp, bt, H1f8,
        nullptr, nullptr, ntiles);
    // conv2 (fp8 gather, fp8 out): H2f8 = dinv * relu(agg(H1f8)@Ws0 + bs0)
    fused_conv<128, false, true, true, false><<<gblk, 256, 0, stream>>>(
        H1f8, row_ptr, edge, dinv, Ws0p, bs, nullptr, nullptr, nullptr, H2f8,
        nullptr, nullptr, ntiles);
    // conv3 (fp8 gather, fused pooling): pooled += per-graph sums of relu(agg@Ws1+bs1)
    fused_conv<128, false, false, false, true><<<gblk, 256, 0, stream>>>(
        H2f8, row_ptr, edge, dinv, Ws1p, bs + 128, nullptr, nullptr, nullptr, nullptr,
        batch, pooled, ntiles);

    // head: out = (pooled/cnt) @ Wo + bo
    head_kernel<<<32, 256, 0, stream>>>(pooled, gstart, Wo, bo, out);
}

// Round 11
// 324.739 us; speedup vs baseline: 1.1498x; 1.0690x over previous
//
#include <hip/hip_runtime.h>

#define N_NODES  100000
#define N_EDGES  1600000
#define N_GRAPHS 512
#define HID      128
#define NB       782        // fine buckets of 128 nodes (dst >> 7)
#define NCHUNK   782        // edge chunks of 2048 (3 blocks/CU for hist+scatter)
#define CHUNK    2048
#define ECAP     512        // LDS edge-span capacity per wave-tile (mean 256, ~8-sigma)

typedef unsigned int  uint;
typedef unsigned char uchar;
typedef unsigned short ushort;
typedef __attribute__((ext_vector_type(8))) short  short8;   // 8 bf16 (4 VGPRs)
typedef __attribute__((ext_vector_type(4))) float  f32x4;
typedef __attribute__((ext_vector_type(2))) float  f32x2;

__device__ inline float bflo(uint u) { return __uint_as_float(u << 16); }
__device__ inline float bfhi(uint u) { return __uint_as_float(u & 0xffff0000u); }
__device__ inline ushort f2bf(float f) {
    uint u = __float_as_uint(f);
    return (ushort)((u + 0x7fffu + ((u >> 16) & 1u)) >> 16);   // RNE
}
__device__ inline uint pk(float a, float b) {
    return (uint)f2bf(a) | ((uint)f2bf(b) << 16);
}

// unmasked 16-fp8 accumulate into f32x2 pairs (v_pk_add_f32 eligible)
__device__ inline void acc16_pk(uint4 hv, f32x2* a) {
    a[0] += __builtin_amdgcn_cvt_pk_f32_fp8((int)hv.x, false);
    a[1] += __builtin_amdgcn_cvt_pk_f32_fp8((int)hv.x, true);
    a[2] += __builtin_amdgcn_cvt_pk_f32_fp8((int)hv.y, false);
    a[3] += __builtin_amdgcn_cvt_pk_f32_fp8((int)hv.y, true);
    a[4] += __builtin_amdgcn_cvt_pk_f32_fp8((int)hv.z, false);
    a[5] += __builtin_amdgcn_cvt_pk_f32_fp8((int)hv.z, true);
    a[6] += __builtin_amdgcn_cvt_pk_f32_fp8((int)hv.w, false);
    a[7] += __builtin_amdgcn_cvt_pk_f32_fp8((int)hv.w, true);
}
// masked variant (tail batch only); w in {0,1} so w* is exact
__device__ inline void acc16_w(uint4 hv, float w, f32x2* a) {
    a[0] += w * __builtin_amdgcn_cvt_pk_f32_fp8((int)hv.x, false);
    a[1] += w * __builtin_amdgcn_cvt_pk_f32_fp8((int)hv.x, true);
    a[2] += w * __builtin_amdgcn_cvt_pk_f32_fp8((int)hv.y, false);
    a[3] += w * __builtin_amdgcn_cvt_pk_f32_fp8((int)hv.y, true);
    a[4] += w * __builtin_amdgcn_cvt_pk_f32_fp8((int)hv.z, false);
    a[5] += w * __builtin_amdgcn_cvt_pk_f32_fp8((int)hv.z, true);
    a[6] += w * __builtin_amdgcn_cvt_pk_f32_fp8((int)hv.w, false);
    a[7] += w * __builtin_amdgcn_cvt_pk_f32_fp8((int)hv.w, true);
}

// ---------------- prep: pack W | boundaries | cvt temb | coarse hist | zero pooled ----
// blocks: [0,224) pack, [224,615) boundary, [615,3740) temb, [3740,4522) hist,
//         [4522,4778) pooled zero
__global__ __launch_bounds__(256)
void prep_kernel(const float* __restrict__ Wt, const float* __restrict__ W1,
                 const float* __restrict__ Ws, ushort* __restrict__ packed,
                 const int* __restrict__ batch, int* __restrict__ gstart,
                 const float* __restrict__ temb, ushort* __restrict__ tembb,
                 const int* __restrict__ dst, int* __restrict__ chunk_hist,
                 float* __restrict__ pooled) {
    __shared__ int h[NB];
    int b = blockIdx.x;
    int t = threadIdx.x;
    if (b < 224) {                          // pack weights into MFMA B-frag order
        int tid = b * 256 + t;
        const float* src; int p; ushort* dstp;
        if (tid < 16384)      { src = Wt;         p = tid;         dstp = packed; }
        else if (tid < 24576) { src = W1;         p = tid - 16384; dstp = packed + 16384; }
        else if (tid < 40960) { src = Ws;         p = tid - 24576; dstp = packed + 24576; }
        else                  { src = Ws + 16384; p = tid - 40960; dstp = packed + 40960; }
        int j  = p & 7;
        int L  = (p >> 3) & 63;
        int cb = (p >> 9) & 7;
        int s  = p >> 12;
        int k  = s * 32 + (L >> 4) * 8 + j;
        int n  = cb * 16 + (L & 15);
        dstp[p] = f2bf(src[k * 128 + n]);
    } else if (b < 615) {                   // graph boundary scan (batch sorted)
        int i = (b - 224) * 256 + t;
        if (i >= N_NODES) return;
        int bb = batch[i];
        int prev = (i == 0) ? -1 : batch[i - 1];
        for (int g = prev + 1; g <= bb; ++g) gstart[g] = i;
        if (i == N_NODES - 1) {
            for (int g = bb + 1; g <= N_GRAPHS; ++g) gstart[g] = N_NODES;
        }
    } else if (b < 3740) {                  // cvt temb (N*128 floats, 16/thread, exact)
        long i = ((long)(b - 615) * 256 + t) * 16;
#pragma unroll
        for (int k = 0; k < 4; ++k) {
            float4 f = *(const float4*)(temb + i + k * 4);
            uint2 o; o.x = pk(f.x, f.y); o.y = pk(f.z, f.w);
            *(uint2*)(tembb + i + k * 4) = o;
        }
    } else if (b < 4522) {                  // coarse histogram per 2048-edge chunk
        int c = b - 3740;
        for (int i = t; i < NB; i += 256) h[i] = 0;
        __syncthreads();
        const int4* d4 = (const int4*)dst;
#pragma unroll
        for (int k = 0; k < 2; ++k) {
            int i4 = c * (CHUNK / 4) + k * 256 + t;
            if (i4 < N_EDGES / 4) {
                int4 d = d4[i4];
                atomicAdd(&h[d.x >> 7], 1);
                atomicAdd(&h[d.y >> 7], 1);
                atomicAdd(&h[d.z >> 7], 1);
                atomicAdd(&h[d.w >> 7], 1);
            }
        }
        __syncthreads();
        for (int i = t; i < NB; i += 256) chunk_hist[c * NB + i] = h[i];
    } else {                                // zero pooled accumulators (512*128)
        pooled[(b - 4522) * 256 + t] = 0.f;
    }
}

// ---------------- CSR build v3: parallel bucketed counting sort ----------------

// scanA: one block per bucket — ordered prefix over 782 chunks (4 vals/thread)
__global__ __launch_bounds__(256)
void scanA(const int* __restrict__ chunk_hist, int* __restrict__ cbaseT,
           int* __restrict__ btotal) {
    __shared__ int sc[256];
    int b = blockIdx.x, t = threadIdx.x;
    int v[4]; int sum = 0;
#pragma unroll
    for (int k = 0; k < 4; ++k) {
        int c = t * 4 + k;
        v[k] = (c < NCHUNK) ? chunk_hist[c * NB + b] : 0;
        sum += v[k];
    }
    sc[t] = sum;
    __syncthreads();
    for (int off = 1; off < 256; off <<= 1) {
        int x = (t >= off) ? sc[t - off] : 0;
        __syncthreads();
        sc[t] += x;
        __syncthreads();
    }
    int run = sc[t] - sum;
#pragma unroll
    for (int k = 0; k < 4; ++k) {
        int c = t * 4 + k;
        if (c < NCHUNK) cbaseT[b * NCHUNK + c] = run;
        run += v[k];
    }
    if (t == 255) btotal[b] = sc[255];
}

// scanB: single tiny block — exclusive scan of 782 bucket totals
__global__ __launch_bounds__(256)
void scanB(const int* __restrict__ btotal, int* __restrict__ bstart,
           int* __restrict__ row_ptr) {
    __shared__ int sc[256];
    int t = threadIdx.x;
    int v[4]; int sum = 0;
#pragma unroll
    for (int k = 0; k < 4; ++k) {
        int idx = t * 4 + k;
        v[k] = (idx < NB) ? btotal[idx] : 0;
        sum += v[k];
    }
    sc[t] = sum;
    __syncthreads();
    for (int off = 1; off < 256; off <<= 1) {
        int x = (t >= off) ? sc[t - off] : 0;
        __syncthreads();
        sc[t] += x;
        __syncthreads();
    }
    int run = sc[t] - sum;
#pragma unroll
    for (int k = 0; k < 4; ++k) {
        int idx = t * 4 + k;
        if (idx < NB) bstart[idx] = run;
        run += v[k];
    }
    if (t == 0) { bstart[NB] = N_EDGES; row_ptr[N_NODES] = N_EDGES; }
}

// scatter: per-chunk into tmp — contiguous runs per bucket (bases = cbaseT + bstart)
__global__ __launch_bounds__(256)
void scatter_coarse(const int* __restrict__ src, const int* __restrict__ dst,
                    const int* __restrict__ cbaseT, const int* __restrict__ bstart,
                    uint* __restrict__ tmp) {
    __shared__ int cur[NB];
    int c = blockIdx.x, t = threadIdx.x;
    for (int i = t; i < NB; i += 256) cur[i] = cbaseT[i * NCHUNK + c] + bstart[i];
    __syncthreads();
    const int4* s4p = (const int4*)src;
    const int4* d4p = (const int4*)dst;
#pragma unroll
    for (int k = 0; k < 2; ++k) {
        int i4 = c * (CHUNK / 4) + k * 256 + t;
        if (i4 < N_EDGES / 4) {
            int4 s = s4p[i4];
            int4 d = d4p[i4];
            int p;
            p = atomicAdd(&cur[d.x >> 7], 1); tmp[p] = (uint)s.x | (((uint)(d.x & 127)) << 17);
            p = atomicAdd(&cur[d.y >> 7], 1); tmp[p] = (uint)s.y | (((uint)(d.y & 127)) << 17);
            p = atomicAdd(&cur[d.z >> 7], 1); tmp[p] = (uint)s.z | (((uint)(d.z & 127)) << 17);
            p = atomicAdd(&cur[d.w >> 7], 1); tmp[p] = (uint)s.w | (((uint)(d.w & 127)) << 17);
        }
    }
}

// csr_fine: one block per 128-node bucket — local hist+scan -> row_ptr/dinv,
// fine scatter, fused xb8 = fp8(dinv * x)
__global__ __launch_bounds__(256)
void csr_fine(const uint* __restrict__ tmp, const int* __restrict__ bstart,
              int* __restrict__ row_ptr, float* __restrict__ dinv,
              int* __restrict__ edge, const float* __restrict__ x,
              uchar* __restrict__ xb8) {
    __shared__ int   cnt[128];
    __shared__ float dvloc[128];
    __shared__ int   ps[128];
    int b = blockIdx.x, t = threadIdx.x;
    int node0 = b << 7;
    int ncnt = min(128, N_NODES - node0);
    int s = bstart[b], e = bstart[b + 1];
    if (t < 128) cnt[t] = 0;
    __syncthreads();
    for (int i = s + t; i < e; i += 256) atomicAdd(&cnt[tmp[i] >> 17], 1);
    __syncthreads();
    int c0 = (t < 128) ? cnt[t] : 0;
    if (t < 128) ps[t] = c0;
    __syncthreads();
    for (int off = 1; off < 128; off <<= 1) {
        int v = (t < 128 && t >= off) ? ps[t - off] : 0;
        __syncthreads();
        if (t < 128) ps[t] += v;
        __syncthreads();
    }
    if (t < 128) {
        int p0 = s + ps[t] - c0;
        float dv = rsqrtf((float)(c0 + 1));
        if (t < ncnt) { row_ptr[node0 + t] = p0; dinv[node0 + t] = dv; }
        dvloc[t] = dv;
        cnt[t] = p0;                         // counts -> absolute cursors
    }
    __syncthreads();
    for (int i = s + t; i < e; i += 256) {
        uint rec = tmp[i];
        int p = atomicAdd(&cnt[rec >> 17], 1);
        edge[p] = (int)(rec & 0x1FFFFu);
    }
    // fused: xb8 rows for this bucket = fp8(dinv * x)  (4 feats -> 1 uint per idx)
    for (int idx = t; idx < ncnt * 16; idx += 256) {
        int row = idx >> 4, q = idx & 15;
        float4 f = ((const float4*)(x + (size_t)(node0 + row) * 64))[q];
        float d = dvloc[row];
        int w = __builtin_amdgcn_cvt_pk_fp8_f32(f.x * d, f.y * d, 0, false);
        w     = __builtin_amdgcn_cvt_pk_fp8_f32(f.z * d, f.w * d, w, true);
        *(uint*)(xb8 + (size_t)(node0 + row) * 64 + q * 4) = (uint)w;
    }
}

// ---------------- fused GCN conv ----------------
// input rows are G = dinv*H (fp8); agg_v = dinv_v * (sum_{s in N(v)} G_s + G_v)
// O = relu(agg @ W + b) [+ relu(tembb @ Wt + bt)]; SCALEOUT: store dinv*O
// R11: (a) degree-balanced row->group assignment (K=128): bitonic sort 16 (deg,row)
// keys via shfl_xor (masks<=8 keep lanes 0-15 self-contained), group g takes ranks
// {g, 15-g} -> wave critical path ~max -> ~mean. (b) edge walk split into full
// unmasked batches (f32x2 packed adds) + one masked tail batch (bit-identical).
template <int K, bool TEMB, bool OUT8, bool SCALEOUT, bool POOL>
__global__ __launch_bounds__(256)
void fused_conv(const void* __restrict__ Hv, const int* __restrict__ rp,
                const int* __restrict__ edge, const float* __restrict__ dinv,
                const ushort* __restrict__ Wp, const float* __restrict__ bias,
                const ushort* __restrict__ tembb, const ushort* __restrict__ Wtp,
                const float* __restrict__ bias_t, void* __restrict__ Ov,
                const int* __restrict__ batchp, float* __restrict__ pooled, int ntiles) {
    constexpr int LPR  = K / 16;      // lanes per row (16 fp8 feats/lane)
    constexpr int G    = 64 / LPR;    // concurrent rows (8 or 16)
    constexpr int RPG  = 16 / G;      // serial rows per group (2 or 1)
    constexpr int U    = 8;           // edge-walk unroll depth
    constexpr int LROW = 136;         // LDS row stride in shorts (bf16 staging)
    __shared__ __align__(16) ushort sA[4][16 * LROW];
    __shared__ uint sE[4][ECAP];      // per-wave edge-span stage
    const int wave = threadIdx.x >> 6;
    const int lane = threadIdx.x & 63;
    const int tile = blockIdx.x * 4 + wave;
    if (tile >= ntiles) return;       // per-wave LDS, no barriers: safe
    const int row0 = tile * 16;
    const int g  = lane / LPR;
    const int fq = lane % LPR;
    ushort* myA = sA[wave];
    const uchar* H8 = (const uchar*)Hv;

    // lane-parallel preload of row_ptr[17] / dinv[16]; broadcast via shfl
    int   rpv = rp[row0 + ((lane < 17) ? lane : 16)];
    float dvv = dinv[row0 + ((lane < 16) ? lane : 15)];

    // ---- stage the tile's contiguous edge span into LDS (coalesced) ----
    const int s0   = __shfl(rpv, 0);
    const int e15  = __shfl(rpv, 16);
    const int ecnt = e15 - s0;
    uint* sEw = sE[wave];
    for (int i = lane; i < ecnt && i < ECAP; i += 64)
        sEw[i] = ((const uint*)edge)[s0 + i];

    // ---- degree-balanced row assignment (RPG==2 only) ----
    int rowA = g, rowB = 0;
    if constexpr (RPG == 2) {
        int r15  = lane & 15;
        int degk = __shfl(rpv, r15 + 1) - __shfl(rpv, r15);
        int key  = degk * 16 + r15;
#pragma unroll
        for (int kk = 2; kk <= 16; kk <<= 1) {
#pragma unroll
            for (int jm = kk >> 1; jm >= 1; jm >>= 1) {
                int other = __shfl_xor(key, jm);
                bool asc = ((lane & kk) == 0);
                bool keepmin = (((lane & jm) == 0) == asc);
                int mn = key < other ? key : other;
                int mx = key < other ? other : key;
                key = keepmin ? mn : mx;
            }
        }
        rowA = __shfl(key, g) & 15;       // g-th smallest degree row
        rowB = __shfl(key, 15 - g) & 15;  // paired with (15-g)-th -> balanced sums
    }

    // ---- phase 1: each group gathers its own RPG rows (16B/lane, no reduce) ----
    auto phase1 = [&](auto eload) {
        for (int rr = 0; rr < RPG; ++rr) {
            int r = (RPG == 2) ? (rr == 0 ? rowA : rowB) : g;
            int v = row0 + r;
            int s = __shfl(rpv, r), e = __shfl(rpv, r + 1);
            f32x2 a[8];
            // self-loop init: a = G_v
            {
                uint4 xv = *(const uint4*)(H8 + (size_t)v * K + fq * 16);
                a[0] = __builtin_amdgcn_cvt_pk_f32_fp8((int)xv.x, false);
                a[1] = __builtin_amdgcn_cvt_pk_f32_fp8((int)xv.x, true);
                a[2] = __builtin_amdgcn_cvt_pk_f32_fp8((int)xv.y, false);
                a[3] = __builtin_amdgcn_cvt_pk_f32_fp8((int)xv.y, true);
                a[4] = __builtin_amdgcn_cvt_pk_f32_fp8((int)xv.z, false);
                a[5] = __builtin_amdgcn_cvt_pk_f32_fp8((int)xv.z, true);
                a[6] = __builtin_amdgcn_cvt_pk_f32_fp8((int)xv.w, false);
                a[7] = __builtin_amdgcn_cvt_pk_f32_fp8((int)xv.w, true);
            }
            int nfull = (e - s) / U;          // group-uniform
            int j = s;
            for (int i = 0; i < nfull; ++i, j += U) {   // full batches: no masks
                int sv[U];
#pragma unroll
                for (int u = 0; u < U; ++u) sv[u] = eload(j + u);
                uint4 hv[U];
#pragma unroll
                for (int u = 0; u < U; ++u)
                    hv[u] = *(const uint4*)(H8 + (size_t)sv[u] * K + fq * 16);
#pragma unroll
                for (int u = 0; u < U; ++u) acc16_pk(hv[u], a);
            }
            if (j < e) {                       // one masked tail batch
                int sv[U];
#pragma unroll
                for (int u = 0; u < U; ++u) {
                    int jv = j + u;
                    int jj = (jv < e) ? jv : e - 1;   // j<e => e>s => e-1 valid
                    sv[u] = eload(jj);
                }
                uint4 hv[U];
#pragma unroll
                for (int u = 0; u < U; ++u)
                    hv[u] = *(const uint4*)(H8 + (size_t)sv[u] * K + fq * 16);
#pragma unroll
                for (int u = 0; u < U; ++u) {
                    float w = (j + u < e) ? 1.0f : 0.0f;
                    acc16_w(hv[u], w, a);
                }
            }
            float dv = __shfl(dvv, r);        // row-uniform scale
            uint4 o1, o2;
            o1.x = pk(a[0].x * dv, a[0].y * dv); o1.y = pk(a[1].x * dv, a[1].y * dv);
            o1.z = pk(a[2].x * dv, a[2].y * dv); o1.w = pk(a[3].x * dv, a[3].y * dv);
            o2.x = pk(a[4].x * dv, a[4].y * dv); o2.y = pk(a[5].x * dv, a[5].y * dv);
            o2.z = pk(a[6].x * dv, a[6].y * dv); o2.w = pk(a[7].x * dv, a[7].y * dv);
            *(uint4*)(myA + r * LROW + fq * 16)     = o1;
            *(uint4*)(myA + r * LROW + fq * 16 + 8) = o2;
        }
    };
    if (ecnt <= ECAP) {
        phase1([&](int jj) { return (int)sEw[jj - s0]; });       // LDS path (normal)
    } else {
        phase1([&](int jj) { return (int)((const uint*)edge)[jj]; });  // fallback
    }

    // ---- phase 2: MFMA (A from LDS, B packed from global/L2) ----
    const int m = lane & 15, q = lane >> 4;
    f32x4 acc[8];
#pragma unroll
    for (int cb = 0; cb < 8; ++cb) acc[cb] = {0.f, 0.f, 0.f, 0.f};
    constexpr int S = K / 32;
#pragma unroll
    for (int s = 0; s < S; ++s) {
        short8 av = *(const short8*)(myA + m * LROW + s * 32 + q * 8);
#pragma unroll
        for (int cb = 0; cb < 8; ++cb) {
            short8 b = *(const short8*)(Wp + (size_t)((s * 8 + cb) * 64 + lane) * 8);
            acc[cb] = __builtin_amdgcn_mfma_f32_16x16x32_bf16(av, b, acc[cb], 0, 0, 0);
        }
    }

    // ---- phase 2b (TEMB): second MFMA chain, A = prepacked bf16 temb rows ----
    f32x4 acc2[TEMB ? 8 : 1];
    if constexpr (TEMB) {
#pragma unroll
        for (int cb = 0; cb < 8; ++cb) acc2[cb] = {0.f, 0.f, 0.f, 0.f};
        const ushort* Arow = tembb + (size_t)(row0 + m) * 128 + q * 8;
#pragma unroll
        for (int s2 = 0; s2 < 4; ++s2) {
            short8 av = *(const short8*)(Arow + s2 * 32);
#pragma unroll
            for (int cb = 0; cb < 8; ++cb) {
                short8 b = *(const short8*)(Wtp + (size_t)((s2 * 8 + cb) * 64 + lane) * 8);
                acc2[cb] = __builtin_amdgcn_mfma_f32_16x16x32_bf16(av, b, acc2[cb], 0, 0, 0);
            }
        }
    }

    // ---- phase 3: epilogue into LDS staging, then store / pool ----
    // C/D layout: col = lane&15, row = (lane>>4)*4 + r
    float dsc[4];
    if constexpr (SCALEOUT) {
#pragma unroll
        for (int r = 0; r < 4; ++r) dsc[r] = __shfl(dvv, q * 4 + r);
    }
    if constexpr (!OUT8) {
        ushort* Ob = (ushort*)Ov;
#pragma unroll
        for (int cb = 0; cb < 8; ++cb) {
            int colc = cb * 16 + m;
            float bv = bias[colc];
            float bt2 = TEMB ? bias_t[colc] : 0.f;
#pragma unroll
            for (int r = 0; r < 4; ++r) {
                int row = q * 4 + r;
                float v = fmaxf(acc[cb][r] + bv, 0.0f);
                if (TEMB) v += fmaxf(acc2[cb][r] + bt2, 0.0f);
                if (SCALEOUT) v *= dsc[r];
                myA[row * LROW + colc] = f2bf(v);
            }
        }
        if constexpr (!POOL) {
#pragma unroll
            for (int i = 0; i < 4; ++i) {
                int srow = i * 4 + (lane >> 4);
                int scol = (lane & 15) * 8;
                *(short8*)(Ob + (size_t)(row0 + srow) * 128 + scol) =
                    *(const short8*)(myA + srow * LROW + scol);
            }
        } else {
            // per-graph segment sums over the 16 rows (batch sorted), 2 cols/lane
            int gidv = (lane < 16) ? batchp[row0 + lane] : 0;
            int colb = lane * 2;
            float p0 = 0.f, p1 = 0.f;
#pragma unroll
            for (int r = 0; r < 16; ++r) {
                uint u = *(const uint*)(myA + r * LROW + colb);
                p0 += bflo(u); p1 += bfhi(u);
                int curg  = __shfl(gidv, r);
                int nextg = (r < 15) ? __shfl(gidv, r + 1) : -1;
                if (nextg != curg) {
                    atomicAdd(&pooled[curg * 128 + colb],     p0);
                    atomicAdd(&pooled[curg * 128 + colb + 1], p1);
                    p0 = 0.f; p1 = 0.f;
                }
            }
        }
    } else {
        uchar* st8 = (uchar*)myA;           // byte staging, row stride 136 B
        uchar* Ob = (uchar*)Ov;
#pragma unroll
        for (int cb = 0; cb < 8; ++cb) {
            int colc = cb * 16 + m;
            float bv = bias[colc];
            float bt2 = TEMB ? bias_t[colc] : 0.f;
#pragma unroll
            for (int r = 0; r < 4; ++r) {
                int row = q * 4 + r;
                float v = fmaxf(acc[cb][r] + bv, 0.0f);
                if (TEMB) v += fmaxf(acc2[cb][r] + bt2, 0.0f);
                if (SCALEOUT) v *= dsc[r];
                int enc = __builtin_amdgcn_cvt_pk_fp8_f32(v, v, 0, false);
                st8[row * 136 + colc] = (uchar)(enc & 0xff);
            }
        }
        // 16 rows * 128 B = 2048 B; 64 lanes * 8 B = 512 B/iter -> 4 iters
#pragma unroll
        for (int i = 0; i < 4; ++i) {
            int idx = i * 64 + lane;        // [0,256)
            int srow = idx >> 4;            // [0,16)
            int soff = (idx & 15) * 8;      // [0,128) step 8
            *(uint2*)(Ob + (size_t)(row0 + srow) * 128 + soff) =
                *(const uint2*)(st8 + srow * 136 + soff);
        }
    }
}

// ---------------- output head: out[g] = (pooled[g]/cnt) @ Wo + bo ----------------

__global__ __launch_bounds__(256)
void head_kernel(const float* __restrict__ pooled, const int* __restrict__ gstart,
                 const float* __restrict__ Wo, const float* __restrict__ bo,
                 float* __restrict__ out) {
    int g  = blockIdx.x * 16 + (threadIdx.x >> 4);
    int tg = threadIdx.x & 15;
    if (g >= N_GRAPHS) return;
    int c = gstart[g + 1] - gstart[g];
    float inv = 1.0f / (float)(c < 1 ? 1 : c);
    float acc = bo[tg];
    for (int k = 0; k < HID; ++k)
        acc += pooled[g * 128 + k] * inv * Wo[k * 16 + tg];
    out[g * 16 + tg] = acc;
}

// ---------------- launch ----------------

extern "C" void kernel_launch(void* const* d_in, const int* in_sizes, int n_in,
                              void* d_out, int out_size, void* d_ws, size_t ws_size,
                              hipStream_t stream) {
    const float* x       = (const float*)d_in[0];
    const int*   ei      = (const int*)d_in[1];
    const float* temb_in = (const float*)d_in[2];
    const int*   batch   = (const int*)d_in[3];
    const float* Wt      = (const float*)d_in[4];
    const float* bt      = (const float*)d_in[5];
    const float* W1      = (const float*)d_in[6];
    const float* b1      = (const float*)d_in[7];
    const float* Ws      = (const float*)d_in[8];
    const float* bs      = (const float*)d_in[9];
    const float* Wo      = (const float*)d_in[10];
    const float* bo      = (const float*)d_in[11];
    float* out = (float*)d_out;

    const int N = N_NODES, E = N_EDGES;
    const int* src = ei;
    const int* dst = ei + E;

    char* p = (char*)d_ws;
    auto carve = [&](size_t bytes) -> void* {
        void* r = (void*)p;
        p += (bytes + 255) & ~(size_t)255;
        return r;
    };
    int*    row_ptr    = (int*)carve((size_t)(N + 1) * 4);
    float*  dinv       = (float*)carve((size_t)N * 4);
    int*    gstart     = (int*)carve((size_t)(N_GRAPHS + 1) * 4);
    ushort* packed     = (ushort*)carve((size_t)57344 * 2);
    int*    chunk_hist = (int*)carve((size_t)NCHUNK * NB * 4);
    int*    cbaseT     = (int*)carve((size_t)NB * NCHUNK * 4);
    int*    btotal     = (int*)carve((size_t)NB * 4);
    int*    bstart     = (int*)carve((size_t)(NB + 1) * 4);
    uint*   tmp        = (uint*)carve((size_t)E * 4);
    int*    edge       = (int*)carve((size_t)E * 4);
    uchar*  xb8        = (uchar*)carve((size_t)(N + 16) * 64);
    ushort* tembb      = (ushort*)carve((size_t)N * 128 * 2);
    uchar*  H1f8       = (uchar*)carve((size_t)(N + 16) * 128);
    uchar*  H2f8       = (uchar*)carve((size_t)(N + 16) * 128);
    float*  pooled     = (float*)carve((size_t)N_GRAPHS * 128 * 4);

    const ushort* Wtp  = packed;
    const ushort* W1p  = packed + 16384;
    const ushort* Ws0p = packed + 24576;
    const ushort* Ws1p = packed + 40960;

    const int ntiles = N / 16;            // 6250
    const int gblk   = (ntiles + 3) / 4;  // 1563

    // prep: pack W | boundaries | cvt temb | coarse hist | zero pooled
    prep_kernel<<<4778, 256, 0, stream>>>(Wt, W1, Ws, packed, batch, gstart,
                                          temb_in, tembb, dst, chunk_hist, pooled);

    // CSR build v3 (parallel scans; 782 buckets x 782 chunks)
    scanA<<<NB, 256, 0, stream>>>(chunk_hist, cbaseT, btotal);
    scanB<<<1, 256, 0, stream>>>(btotal, bstart, row_ptr);
    scatter_coarse<<<NCHUNK, 256, 0, stream>>>(src, dst, cbaseT, bstart, tmp);
    csr_fine<<<NB, 256, 0, stream>>>(tmp, bstart, row_ptr, dinv, edge, x, xb8);

    // conv1 (+fused temb layer): H1f8 = dinv * (relu(agg(G0)@W1+b1) + relu(tembb@Wt+bt))
    fused_conv<64, true, true, true, false><<<gblk, 256, 0, stream>>>(
        xb8, row_ptr, edge, dinv, W1p, b1, tembb, Wtp, bt, H1f8,
        nullptr, nullptr, ntiles);
    // conv2 (fp8 gather, fp8 out): H2f8 = dinv * relu(agg(H1f8)@Ws0 + bs0)
    fused_conv<128, false, true, true, false><<<gblk, 256, 0, stream>>>(
        H1f8, row_ptr, edge, dinv, Ws0p, bs, nullptr, nullptr, nullptr, H2f8,
        nullptr, nullptr, ntiles);
    // conv3 (fp8 gather, fused pooling): pooled += per-graph sums of relu(agg@Ws1+bs1)
    fused_conv<128, false, false, false, true><<<gblk, 256, 0, stream>>>(
        H2f8, row_ptr, edge, dinv, Ws1p, bs + 128, nullptr, nullptr, nullptr, nullptr,
        batch, pooled, ntiles);

    // head: out = (pooled/cnt) @ Wo + bo
    head_kernel<<<32, 256, 0, stream>>>(pooled, gstart, Wo, bo, out);
}